// Round 6
// baseline (675.474 us; speedup 1.0000x reference)
//
#include <hip/hip_runtime.h>
#include <math.h>

typedef unsigned short u16;
typedef unsigned int u32;

// ---- problem constants ----
constexpr int Bb = 4, Ll = 2048, DM = 1024, DI = 2048, DS = 16, DTR = 64, KC = 4;
constexpr int M = Bb * Ll;            // 8192 rows
constexpr int NPAD = 128;             // padded x_dbl width (64 + 2*16 = 96 -> 128)
constexpr int NCHUNK = 32;            // scan chunks
constexpr int LC = Ll / NCHUNK;       // 64 steps per chunk
constexpr int LDXZ = 4096;            // xz row stride (xr|z interleaved)

// ---- bf16 helpers on raw u16 ----
__device__ __forceinline__ float b2f(u16 u) {
    return __uint_as_float(((u32)u) << 16);
}
__device__ __forceinline__ u16 f2b(float f) {
    u32 x = __float_as_uint(f);
    u32 r = (x + 0x7fffu + ((x >> 16) & 1u)) >> 16;   // round-to-nearest-even
    return (u16)r;
}

typedef __attribute__((ext_vector_type(8))) short short8;
typedef __attribute__((ext_vector_type(4))) short short4v;
typedef __attribute__((ext_vector_type(4))) float floatx4;

// async global->LDS, 16B per lane; LDS dest = wave-uniform base + lane*16
__device__ __forceinline__ void gload16(const u16* g, u16* l) {
    __builtin_amdgcn_global_load_lds(
        (const __attribute__((address_space(1))) void*)g,
        (__attribute__((address_space(3))) void*)l,
        16, 0, 0);
}

// a^(s+1) for s=0..15 from base a, tree form (15 muls, depth 4)
__device__ __forceinline__ void pow_tree(float a, float* aa) {
    float a2 = a * a, a4 = a2 * a2, a8 = a4 * a4;
    aa[0] = a;        aa[1] = a2;       aa[2] = a * a2;   aa[3] = a4;
    aa[4] = a * a4;   aa[5] = a2 * a4;  aa[6] = aa[2] * a4; aa[7] = a8;
    aa[8] = a * a8;   aa[9] = a2 * a8;  aa[10] = aa[2] * a8; aa[11] = a4 * a8;
    aa[12] = aa[4] * a8; aa[13] = aa[5] * a8; aa[14] = aa[6] * a8; aa[15] = a8 * a8;
}

// XCD-chunked bijective blockIdx swizzle (T1, m204-style).
template<int GX, int GY>
__device__ __forceinline__ void xcd_swizzle(int& bx, int& by) {
    const int bid = blockIdx.y * GX + blockIdx.x;
    const int xcd = bid & 7;
    const int i = bid >> 3;
    const int c_local = i >> 5;
    const int within = i & 31;
    const int lx = within & 7, ly = within >> 3;
    const int chunk = xcd + c_local * 8;
    constexpr int CXN = GX / 8;
    const int cx = chunk % CXN;
    const int cy = chunk / CXN;
    bx = cx * 8 + lx;
    by = cy * 4 + ly;
}

// =====================================================================
// Big-tile GEMM: 256x256 tile, 8 waves (2M x 4N), BK=32, 4-deep
// circular LDS buffer, one phase per K-tile, counted vmcnt(8),
// setprio, XCD swizzle.  846 TF @ K=1024 (R4) = catalog level (m248).
// OUTM: 0 = bf16 store, 1 = fp32 store.  Grid must be (16, 32).
// =====================================================================
template<int OUTM>
__global__ __launch_bounds__(512, 2) void gemm256(
    const u16* __restrict__ A, const u16* __restrict__ Bm,
    void* __restrict__ Cv,
    int K, int lda, int ldb, int ldc)
{
    __shared__ alignas(16) u16 ldsA[4][256 * 32];   // 64 KiB
    __shared__ alignas(16) u16 ldsB[4][256 * 32];   // 64 KiB

    int bx, by;
    xcd_swizzle<16, 32>(bx, by);

    const int lane = threadIdx.x & 63;
    const int wave = threadIdx.x >> 6;
    const int wr = wave >> 2;
    const int wc = wave & 3;
    const int m0 = by * 256;
    const int n0 = bx * 256;

    const int lrow = lane >> 2;
    const int skc  = (((lane & 3) + (lane >> 3)) & 3) * 8;
    const u16* pA = A  + (size_t)(m0 + wave * 32 + lrow) * lda + skc;
    const u16* pB = Bm + (size_t)(n0 + wave * 32 + lrow) * ldb + skc;
    const int ldst = wave * 1024;

    const int r16 = lane & 15;
    const int quad = lane >> 4;
    const int slot = (quad + 4 - ((r16 >> 1) & 3)) & 3;
    const int aoff = (wr * 128 + r16) * 32 + slot * 8;
    const int boff = (wc * 64  + r16) * 32 + slot * 8;

    const int NT = K >> 5;

    floatx4 acc[8][4] = {};

#pragma unroll
    for (int t = 0; t < 3; ++t) {
        gload16(pA + t * 32,            &ldsA[t][ldst]);
        gload16(pA + t * 32 + 16 * lda, &ldsA[t][ldst + 512]);
        gload16(pB + t * 32,            &ldsB[t][ldst]);
        gload16(pB + t * 32 + 16 * ldb, &ldsB[t][ldst + 512]);
    }
    asm volatile("s_waitcnt vmcnt(8)" ::: "memory");
    __builtin_amdgcn_sched_barrier(0);
    __builtin_amdgcn_s_barrier();

    for (int t = 0; t < NT; ++t) {
        const u16* la = &ldsA[t & 3][aoff];
        const u16* lb = &ldsB[t & 3][boff];
        short8 af[8], bf[4];
#pragma unroll
        for (int i = 0; i < 8; ++i) af[i] = *(const short8*)(la + i * 512);
#pragma unroll
        for (int j = 0; j < 4; ++j) bf[j] = *(const short8*)(lb + j * 512);
        if (t + 3 < NT) {
            const u16* sA = pA + (t + 3) * 32;
            const u16* sB = pB + (t + 3) * 32;
            u16* dA = &ldsA[(t + 3) & 3][ldst];
            u16* dB = &ldsB[(t + 3) & 3][ldst];
            gload16(sA, dA);
            gload16(sA + 16 * lda, dA + 512);
            gload16(sB, dB);
            gload16(sB + 16 * ldb, dB + 512);
        }
        __builtin_amdgcn_sched_barrier(0);
        __builtin_amdgcn_s_barrier();
        asm volatile("s_waitcnt lgkmcnt(0)" ::: "memory");
        __builtin_amdgcn_sched_barrier(0);
        __builtin_amdgcn_s_setprio(1);
#pragma unroll
        for (int i = 0; i < 8; ++i)
#pragma unroll
            for (int j = 0; j < 4; ++j)
                acc[i][j] = __builtin_amdgcn_mfma_f32_16x16x32_bf16(
                    af[i], bf[j], acc[i][j], 0, 0, 0);
        __builtin_amdgcn_s_setprio(0);
        if (t + 3 < NT)      asm volatile("s_waitcnt vmcnt(8)" ::: "memory");
        else if (t + 2 < NT) asm volatile("s_waitcnt vmcnt(4)" ::: "memory");
        else if (t + 1 < NT) asm volatile("s_waitcnt vmcnt(0)" ::: "memory");
        __builtin_amdgcn_sched_barrier(0);
        __builtin_amdgcn_s_barrier();
    }

    const int mw = m0 + wr * 128;
    const int nw = n0 + wc * 64;
    const int rb = quad * 4;
#pragma unroll
    for (int i = 0; i < 8; ++i) {
#pragma unroll
        for (int j = 0; j < 4; ++j) {
            const int n = nw + j * 16 + r16;
#pragma unroll
            for (int r = 0; r < 4; ++r) {
                const int m = mw + i * 16 + rb + r;
                float v = acc[i][j][r];
                if (OUTM == 1)
                    ((float*)Cv)[(size_t)m * ldc + n] = v;
                else
                    ((u16*)Cv)[(size_t)m * ldc + n] = f2b(v);
            }
        }
    }
}

// =====================================================================
// 256x128-tile variant for GEMM6 (N=1024).  3-deep circular buffer,
// 2 blocks/CU, XCD swizzle.  Grid must be (8, 32).
// =====================================================================
template<int OUTM>
__global__ __launch_bounds__(512, 4) void gemm256n128(
    const u16* __restrict__ A, const u16* __restrict__ Bm,
    void* __restrict__ Cv,
    int K, int lda, int ldb, int ldc)
{
    __shared__ alignas(16) u16 ldsA[3][256 * 32];   // 48 KiB
    __shared__ alignas(16) u16 ldsB[3][128 * 32];   // 24 KiB

    int bx, by;
    xcd_swizzle<8, 32>(bx, by);

    const int lane = threadIdx.x & 63;
    const int wave = threadIdx.x >> 6;
    const int wr = wave >> 1;
    const int wc = wave & 1;
    const int m0 = by * 256;
    const int n0 = bx * 128;

    const int lrow = lane >> 2;
    const int skc  = (((lane & 3) + (lane >> 3)) & 3) * 8;
    const u16* pA = A  + (size_t)(m0 + wave * 32 + lrow) * lda + skc;
    const u16* pB = Bm + (size_t)(n0 + wave * 16 + lrow) * ldb + skc;
    const int ldstA = wave * 1024;
    const int ldstB = wave * 512;

    const int r16 = lane & 15;
    const int quad = lane >> 4;
    const int slot = (quad + 4 - ((r16 >> 1) & 3)) & 3;
    const int aoff = (wr * 64 + r16) * 32 + slot * 8;
    const int boff = (wc * 64 + r16) * 32 + slot * 8;

    const int NT = K >> 5;

    floatx4 acc[4][4] = {};

#pragma unroll
    for (int t = 0; t < 2; ++t) {
        gload16(pA + t * 32,            &ldsA[t][ldstA]);
        gload16(pA + t * 32 + 16 * lda, &ldsA[t][ldstA + 512]);
        gload16(pB + t * 32,            &ldsB[t][ldstB]);
    }
    asm volatile("s_waitcnt vmcnt(3)" ::: "memory");
    __builtin_amdgcn_sched_barrier(0);
    __builtin_amdgcn_s_barrier();

    int bc = 0, bs = 2;
    for (int t = 0; t < NT; ++t) {
        const u16* la = &ldsA[bc][aoff];
        const u16* lb = &ldsB[bc][boff];
        short8 af[4], bf[4];
#pragma unroll
        for (int i = 0; i < 4; ++i) af[i] = *(const short8*)(la + i * 512);
#pragma unroll
        for (int j = 0; j < 4; ++j) bf[j] = *(const short8*)(lb + j * 512);
        if (t + 2 < NT) {
            const u16* sa = pA + (t + 2) * 32;
            u16* da = &ldsA[bs][ldstA];
            gload16(sa, da);
            gload16(sa + 16 * lda, da + 512);
            gload16(pB + (t + 2) * 32, &ldsB[bs][ldstB]);
        }
        __builtin_amdgcn_sched_barrier(0);
        __builtin_amdgcn_s_barrier();
        asm volatile("s_waitcnt lgkmcnt(0)" ::: "memory");
        __builtin_amdgcn_sched_barrier(0);
        __builtin_amdgcn_s_setprio(1);
#pragma unroll
        for (int i = 0; i < 4; ++i)
#pragma unroll
            for (int j = 0; j < 4; ++j)
                acc[i][j] = __builtin_amdgcn_mfma_f32_16x16x32_bf16(
                    af[i], bf[j], acc[i][j], 0, 0, 0);
        __builtin_amdgcn_s_setprio(0);
        if (t + 2 < NT)      asm volatile("s_waitcnt vmcnt(3)" ::: "memory");
        else if (t + 1 < NT) asm volatile("s_waitcnt vmcnt(0)" ::: "memory");
        __builtin_amdgcn_sched_barrier(0);
        __builtin_amdgcn_s_barrier();
        bc = (bc == 2) ? 0 : bc + 1;
        bs = (bs == 2) ? 0 : bs + 1;
    }

    const int mw = m0 + wr * 64;
    const int nw = n0 + wc * 64;
    const int rb = quad * 4;
#pragma unroll
    for (int i = 0; i < 4; ++i) {
#pragma unroll
        for (int j = 0; j < 4; ++j) {
            const int n = nw + j * 16 + r16;
#pragma unroll
            for (int r = 0; r < 4; ++r) {
                const int m = mw + i * 16 + rb + r;
                float v = acc[i][j][r];
                if (OUTM == 1)
                    ((float*)Cv)[(size_t)m * ldc + n] = v;
                else
                    ((u16*)Cv)[(size_t)m * ldc + n] = f2b(v);
            }
        }
    }
}

// =====================================================================
// m97-structure GEMM, kept for GEMM4 (OUTM=2: softplus+bias epilogue).
// =====================================================================
template<int OUTM>
__global__ __launch_bounds__(256) void gemm_bt(
    const u16* __restrict__ A, const u16* __restrict__ Bm,
    void* __restrict__ Cv, const float* __restrict__ bias,
    int K, int lda, int ldb, int ldc)
{
    __shared__ alignas(16) u16 ldsA[128 * 32];
    __shared__ alignas(16) u16 ldsB[128 * 32];

    const int lane = threadIdx.x & 63;
    const int wave = threadIdx.x >> 6;
    const int wr = wave >> 1, wc = wave & 1;
    const int m0 = blockIdx.y * 128;
    const int n0 = blockIdx.x * 128;

    const int srow = wave * 32 + (lane >> 2);
    const int skc  = (((lane & 3) + (lane >> 3)) & 3) * 8;
    const u16* Ag = A + (size_t)(m0 + srow) * lda + skc;
    const u16* Bg = Bm + (size_t)(n0 + srow) * ldb + skc;
    u16* lA = &ldsA[wave * 1024];
    u16* lB = &ldsB[wave * 1024];

    const int r16 = lane & 15;
    const int quad = lane >> 4;
    const int slot = (quad + 4 - ((r16 >> 1) & 3)) & 3;
    const u16* arow = &ldsA[(wr * 64 + r16) * 32 + slot * 8];
    const u16* brow = &ldsB[(wc * 64 + r16) * 32 + slot * 8];

    floatx4 acc[4][4] = {};

    for (int k0 = 0; k0 < K; k0 += 32) {
        gload16(Ag + k0,                    lA);
        gload16(Ag + k0 + (size_t)16 * lda, lA + 512);
        gload16(Bg + k0,                    lB);
        gload16(Bg + k0 + (size_t)16 * ldb, lB + 512);
        __syncthreads();

        short8 af[4], bf[4];
#pragma unroll
        for (int i = 0; i < 4; i++) af[i] = *(const short8*)(arow + i * 16 * 32);
#pragma unroll
        for (int j = 0; j < 4; j++) bf[j] = *(const short8*)(brow + j * 16 * 32);
#pragma unroll
        for (int i = 0; i < 4; i++)
#pragma unroll
            for (int j = 0; j < 4; j++)
                acc[i][j] = __builtin_amdgcn_mfma_f32_16x16x32_bf16(
                    af[i], bf[j], acc[i][j], 0, 0, 0);
        __syncthreads();
    }

    const int mw = m0 + wr * 64;
    const int nw = n0 + wc * 64;
    const int rb = quad * 4;
#pragma unroll
    for (int i = 0; i < 4; i++) {
#pragma unroll
        for (int j = 0; j < 4; j++) {
            const int n = nw + j * 16 + r16;
#pragma unroll
            for (int r = 0; r < 4; r++) {
                const int m = mw + i * 16 + rb + r;
                float v = acc[i][j][r];
                if (OUTM == 2) {
                    v += bias[n];
                    v = (v > 20.f) ? v : log1pf(__expf(v));
                }
                if (OUTM == 1)
                    ((float*)Cv)[(size_t)m * ldc + n] = v;
                else
                    ((u16*)Cv)[(size_t)m * ldc + n] = f2b(v);
            }
        }
    }
}

// =====================================================================
// GEMM3 split-K x4 (K=512 each) + FUSED last-block redk.
// Writers: fp32 partials -> part[z][m][n].  Each block then arrives at
// ctr[m-block]; the 4th arrival (device-scope atomic, writers fenced)
// reduces rows m0..m0+127 -> compact bf16 xdbl(64) + fp32 bcf.
// Standard split-K fixup pattern: no spin-wait, no residency assumption.
// Grid (1, 64, 4).
// =====================================================================
__global__ __launch_bounds__(256) void gemm3_redk(
    const u16* __restrict__ A, const u16* __restrict__ Bm,
    float* __restrict__ part, u16* __restrict__ xdbl,
    float* __restrict__ bcf, u32* __restrict__ ctr)
{
    __shared__ alignas(16) u16 ldsA[128 * 32];
    __shared__ alignas(16) u16 ldsB[128 * 32];
    __shared__ int amLast;

    const int lane = threadIdx.x & 63;
    const int wave = threadIdx.x >> 6;
    const int wr = wave >> 1, wc = wave & 1;
    const int m0 = blockIdx.y * 128;
    constexpr int K = DI / 4;                 // 512
    const int koff = blockIdx.z * K;

    const int srow = wave * 32 + (lane >> 2);
    const int skc  = (((lane & 3) + (lane >> 3)) & 3) * 8;
    const u16* Ag = A + (size_t)(m0 + srow) * DI + skc + koff;
    const u16* Bg = Bm + (size_t)srow * DI + skc + koff;     // n0 = 0
    u16* lA = &ldsA[wave * 1024];
    u16* lB = &ldsB[wave * 1024];

    const int r16 = lane & 15;
    const int quad = lane >> 4;
    const int slot = (quad + 4 - ((r16 >> 1) & 3)) & 3;
    const u16* arow = &ldsA[(wr * 64 + r16) * 32 + slot * 8];
    const u16* brow = &ldsB[(wc * 64 + r16) * 32 + slot * 8];

    floatx4 acc[4][4] = {};

    for (int k0 = 0; k0 < K; k0 += 32) {
        gload16(Ag + k0,                   lA);
        gload16(Ag + k0 + (size_t)16 * DI, lA + 512);
        gload16(Bg + k0,                   lB);
        gload16(Bg + k0 + (size_t)16 * DI, lB + 512);
        __syncthreads();

        short8 af[4], bf[4];
#pragma unroll
        for (int i = 0; i < 4; i++) af[i] = *(const short8*)(arow + i * 16 * 32);
#pragma unroll
        for (int j = 0; j < 4; j++) bf[j] = *(const short8*)(brow + j * 16 * 32);
#pragma unroll
        for (int i = 0; i < 4; i++)
#pragma unroll
            for (int j = 0; j < 4; j++)
                acc[i][j] = __builtin_amdgcn_mfma_f32_16x16x32_bf16(
                    af[i], bf[j], acc[i][j], 0, 0, 0);
        __syncthreads();
    }

    const int mw = m0 + wr * 64;
    const int nw = wc * 64;
    const int rb = quad * 4;
#pragma unroll
    for (int i = 0; i < 4; i++) {
#pragma unroll
        for (int j = 0; j < 4; j++) {
            const int n = nw + j * 16 + r16;
#pragma unroll
            for (int r = 0; r < 4; r++) {
                const int m = mw + i * 16 + rb + r;
                part[((size_t)blockIdx.z * M + m) * NPAD + n] = acc[i][j][r];
            }
        }
    }

    // ---- last-arrival reduce (redk) ----
    __threadfence();
    if (threadIdx.x == 0)
        amLast = (atomicAdd(&ctr[blockIdx.y], 1u) == 3u);
    __syncthreads();
    if (!amLast) return;
    __threadfence();

    for (int it = threadIdx.x; it < 128 * 24; it += 256) {
        const int r = it / 24;
        const int n4 = (it - r * 24) * 4;
        const int m = m0 + r;
        const size_t stride = (size_t)M * NPAD;
        const float* p = part + (size_t)m * NPAD + n4;
        floatx4 a4 = *(const floatx4*)(p)
                   + *(const floatx4*)(p + stride)
                   + *(const floatx4*)(p + 2 * stride)
                   + *(const floatx4*)(p + 3 * stride);
        if (n4 < 64) {
            short4v ob;
#pragma unroll
            for (int j = 0; j < 4; j++) ob[j] = (short)f2b(a4[j]);
            *(short4v*)(xdbl + (size_t)m * 64 + n4) = ob;
        } else {
            *(floatx4*)(bcf + (size_t)m * 32 + (n4 - 64)) = a4;
        }
    }
}

// =====================================================================
// merged operand prep: counters zero | x cvt | W cvt/pad
// =====================================================================
__global__ __launch_bounds__(256) void prep_all(
    const float* __restrict__ x, const float* __restrict__ W_in,
    const float* __restrict__ W_x, const float* __restrict__ W_dt,
    const float* __restrict__ W_out,
    u16* __restrict__ xbf, u16* __restrict__ wibf, u16* __restrict__ wxp,
    u16* __restrict__ wdtb, u16* __restrict__ woutb, u32* __restrict__ ctrs)
{
    constexpr int N0 = M * DM;
    constexpr int N1 = 2 * DI * DM;
    constexpr int N2 = NPAD * DI;
    constexpr int N3 = DI * DTR;
    if (blockIdx.x == 0 && threadIdx.x < 96) ctrs[threadIdx.x] = 0;
    int idx = blockIdx.x * blockDim.x + threadIdx.x;
    if (idx < N0) {
        xbf[idx] = f2b(x[idx]);
        return;
    }
    idx -= N0;
    if (idx < N1) {
        wibf[idx] = f2b(W_in[idx]);
    } else if (idx < N1 + N2) {
        int i = idx - N1;
        int r = i >> 11, c = i & 2047;
        wxp[i] = (r < 96) ? f2b(W_x[r * 2048 + c]) : (u16)0;
    } else if (idx < N1 + N2 + N3) {
        int i = idx - N1 - N2;
        wdtb[i] = f2b(W_dt[i]);
    } else {
        int i = idx - N1 - N2 - N3;
        woutb[i] = f2b(W_out[i]);
    }
}

// =====================================================================
// Depthwise causal conv (K=4) + SiLU, vectorized.
// =====================================================================
__global__ __launch_bounds__(256) void conv_silu(
    const u16* __restrict__ xz, const float* __restrict__ conv_w,
    const float* __restrict__ conv_b, u16* __restrict__ xs)
{
    const int m = blockIdx.x;
    const int d0 = threadIdx.x * 8;
    const int l = m & (Ll - 1);

    float acc[8];
    {
        floatx4 cb0 = *(const floatx4*)(conv_b + d0);
        floatx4 cb1 = *(const floatx4*)(conv_b + d0 + 4);
#pragma unroll
        for (int j = 0; j < 4; j++) { acc[j] = cb0[j]; acc[4 + j] = cb1[j]; }
    }
    float w[8][KC];
#pragma unroll
    for (int jd = 0; jd < 8; jd++) {
        floatx4 wv = *(const floatx4*)(conv_w + (d0 + jd) * KC);
#pragma unroll
        for (int k = 0; k < KC; k++) w[jd][k] = wv[k];
    }
#pragma unroll
    for (int k = 0; k < KC; k++) {
        int li = l - (KC - 1) + k;
        if (li >= 0) {
            short8 xv = *(const short8*)(xz + (size_t)(m - (KC - 1) + k) * LDXZ + d0);
#pragma unroll
            for (int jd = 0; jd < 8; jd++)
                acc[jd] += b2f((u16)xv[jd]) * w[jd][k];
        }
    }
    short8 o;
#pragma unroll
    for (int jd = 0; jd < 8; jd++) {
        float s = acc[jd] / (1.f + __expf(-acc[jd]));
        o[jd] = (short)f2b(s);
    }
    *(short8*)(xs + (size_t)m * DI + d0) = o;
}

// =====================================================================
// Chunked selective scan phase 1 + FUSED last-block chunk-prefix (p2).
// p1: per-(channel, chunk) thread computes h_end + sdt.  Then arrives at
// ctr2[b*8 + dblk]; the 32nd arrival reconstructs P = exp(a_s * sdt)
// and runs the 32-chunk prefix IN-PLACE over scr_h for its 256 channels.
// Grid (8, 4, 32).
// =====================================================================
__global__ __launch_bounds__(256) void scan_p1p2(
    const u16* __restrict__ xzdt, const u16* __restrict__ xs,
    const float* __restrict__ bcf, const float* __restrict__ A_log,
    float* __restrict__ scr_h, float* __restrict__ sdt_g,
    u32* __restrict__ ctr2)
{
    __shared__ alignas(16) float bcs[LC * 32];   // 8 KB
    __shared__ int last;

    const int d = blockIdx.x * 256 + threadIdx.x;
    const int b = blockIdx.y;
    const int c = blockIdx.z;
    const int m0 = b * Ll + c * LC;

    {
        const float* bc_g = bcf + (size_t)m0 * 32;
#pragma unroll
        for (int j = 0; j < 2; j++) {
            int idx = j * 1024 + threadIdx.x * 4;
            *(floatx4*)(bcs + idx) = *(const floatx4*)(bc_g + idx);
        }
    }

    const float ad0 = -__expf(A_log[0]);
    float adl[DS];
    bool fast = true;
#pragma unroll
    for (int s = 0; s < DS; s++) {
        float av = -__expf(A_log[s]);
        adl[s] = av;
        float kr = (float)(s + 1);
        if (fabsf(av / ad0 - kr) > 1e-4f * kr) fast = false;
    }

    const u16* dt_p = xzdt + (size_t)m0 * LDXZ + d;
    const u16* xs_p = xs + (size_t)m0 * DI + d;

    float h[DS] = {};
    float sdt = 0.f;

    __syncthreads();

    u16 dt_c = dt_p[0],     xs_c = xs_p[0];
    u16 dt_1 = dt_p[LDXZ],  xs_1 = xs_p[DI];

    if (fast) {
        for (int l = 0; l < LC; l++) {
            u16 dt_2 = dt_p[2 * LDXZ];
            u16 xs_2 = xs_p[2 * DI];
            const float* bl = bcs + l * 32;
            floatx4 B0 = *(const floatx4*)(bl);
            floatx4 B1 = *(const floatx4*)(bl + 4);
            floatx4 B2 = *(const floatx4*)(bl + 8);
            floatx4 B3 = *(const floatx4*)(bl + 12);

            float dtv = b2f(dt_c);
            float xv  = b2f(xs_c);
            float bx = dtv * xv;
            sdt += dtv;
            float aa[DS];
            pow_tree(__expf(dtv * ad0), aa);
#pragma unroll
            for (int s = 0; s < DS; s++) {
                float Bv = (s < 4) ? B0[s] : (s < 8) ? B1[s - 4]
                         : (s < 12) ? B2[s - 8] : B3[s - 12];
                h[s] = aa[s] * h[s] + bx * Bv;
            }
            dt_c = dt_1; dt_1 = dt_2; xs_c = xs_1; xs_1 = xs_2;
            dt_p += LDXZ; xs_p += DI;
        }
    } else {
        for (int l = 0; l < LC; l++) {
            u16 dt_2 = dt_p[2 * LDXZ];
            u16 xs_2 = xs_p[2 * DI];
            const float* bl = bcs + l * 32;
            floatx4 B0 = *(const floatx4*)(bl);
            floatx4 B1 = *(const floatx4*)(bl + 4);
            floatx4 B2 = *(const floatx4*)(bl + 8);
            floatx4 B3 = *(const floatx4*)(bl + 12);

            float dtv = b2f(dt_c);
            float xv  = b2f(xs_c);
            float bx = dtv * xv;
            sdt += dtv;
#pragma unroll
            for (int s = 0; s < DS; s++) {
                float Bv = (s < 4) ? B0[s] : (s < 8) ? B1[s - 4]
                         : (s < 12) ? B2[s - 8] : B3[s - 12];
                float a = __expf(dtv * adl[s]);
                h[s] = a * h[s] + bx * Bv;
            }
            dt_c = dt_1; dt_1 = dt_2; xs_c = xs_1; xs_1 = xs_2;
            dt_p += LDXZ; xs_p += DI;
        }
    }

    const size_t base = ((size_t)(b * NCHUNK + c) * DI + d) * DS;
#pragma unroll
    for (int s = 0; s < DS; s += 4) {
        floatx4 hv = {h[s], h[s+1], h[s+2], h[s+3]};
        *(floatx4*)(scr_h + base + s) = hv;
    }
    sdt_g[(size_t)(b * NCHUNK + c) * DI + d] = sdt;

    // ---- last-arrival chunk-prefix (p2), in-place on scr_h ----
    __threadfence();
    if (threadIdx.x == 0)
        last = (atomicAdd(&ctr2[b * 8 + blockIdx.x], 1u) == (u32)(NCHUNK - 1));
    __syncthreads();
    if (!last) return;
    __threadfence();

    float hin[DS];
#pragma unroll
    for (int s = 0; s < DS; s++) hin[s] = 0.f;
    for (int cc = 0; cc < NCHUNK; cc++) {
        const size_t cb = ((size_t)(b * NCHUNK + cc) * DI + d) * DS;
        const float sv = sdt_g[(size_t)(b * NCHUNK + cc) * DI + d];
        float P[DS];
        if (fast) {
            pow_tree(__expf(ad0 * sv), P);
        } else {
#pragma unroll
            for (int s = 0; s < DS; s++) P[s] = __expf(adl[s] * sv);
        }
        floatx4 he0 = *(const floatx4*)(scr_h + cb);
        floatx4 he1 = *(const floatx4*)(scr_h + cb + 4);
        floatx4 he2 = *(const floatx4*)(scr_h + cb + 8);
        floatx4 he3 = *(const floatx4*)(scr_h + cb + 12);
        floatx4 o0 = {hin[0], hin[1], hin[2], hin[3]};
        floatx4 o1 = {hin[4], hin[5], hin[6], hin[7]};
        floatx4 o2 = {hin[8], hin[9], hin[10], hin[11]};
        floatx4 o3 = {hin[12], hin[13], hin[14], hin[15]};
        *(floatx4*)(scr_h + cb)      = o0;
        *(floatx4*)(scr_h + cb + 4)  = o1;
        *(floatx4*)(scr_h + cb + 8)  = o2;
        *(floatx4*)(scr_h + cb + 12) = o3;
#pragma unroll
        for (int s = 0; s < DS; s++) {
            float he = (s < 4) ? he0[s] : (s < 8) ? he1[s - 4]
                     : (s < 12) ? he2[s - 8] : he3[s - 12];
            hin[s] = P[s] * hin[s] + he;
        }
    }
}

__global__ __launch_bounds__(256) void scan_p3(
    const u16* __restrict__ xz, const u16* xs, const float* __restrict__ bcf,
    const float* __restrict__ scr_hin, const float* __restrict__ A_log,
    const float* __restrict__ Dvec, u16* yg)
{
    __shared__ alignas(16) float bcs[LC * 32];   // 8 KB

    const int d = blockIdx.x * 256 + threadIdx.x;
    const int b = blockIdx.y;
    const int c = blockIdx.z;
    const int m0 = b * Ll + c * LC;

    {
        const float* bc_g = bcf + (size_t)m0 * 32;
#pragma unroll
        for (int j = 0; j < 2; j++) {
            int idx = j * 1024 + threadIdx.x * 4;
            *(floatx4*)(bcs + idx) = *(const floatx4*)(bc_g + idx);
        }
    }

    const float ad0 = -__expf(A_log[0]);
    float adl[DS];
    bool fast = true;
#pragma unroll
    for (int s = 0; s < DS; s++) {
        float av = -__expf(A_log[s]);
        adl[s] = av;
        float kr = (float)(s + 1);
        if (fabsf(av / ad0 - kr) > 1e-4f * kr) fast = false;
    }
    const float Dd = Dvec[d];

    const u16* dt_p = xz + (size_t)m0 * LDXZ + d;
    const u16* z_p  = xz + (size_t)m0 * LDXZ + 2048 + d;
    const u16* xs_p = xs + (size_t)m0 * DI + d;
    u16* yg_p = yg + (size_t)m0 * DI + d;

    float h[DS];
    const size_t base = ((size_t)(b * NCHUNK + c) * DI + d) * DS;
#pragma unroll
    for (int s = 0; s < DS; s += 4) {
        floatx4 hv = *(const floatx4*)(scr_hin + base + s);
        h[s] = hv[0]; h[s+1] = hv[1]; h[s+2] = hv[2]; h[s+3] = hv[3];
    }

    __syncthreads();

    u16 dt_c = dt_p[0],    dt_1 = dt_p[LDXZ];
    u16 xs_c = xs_p[0],    xs_1 = xs_p[DI];
    u16 z_c  = z_p[0],     z_1  = z_p[LDXZ];

    for (int l = 0; l < LC; l++) {
        u16 dt_2 = dt_p[2 * LDXZ];
        u16 xs_2 = xs_p[2 * DI];
        u16 z_2  = z_p[2 * LDXZ];
        const float* bl = bcs + l * 32;
        floatx4 Bq[4], Cq[4];
#pragma unroll
        for (int q = 0; q < 4; q++) {
            Bq[q] = *(const floatx4*)(bl + q * 4);
            Cq[q] = *(const floatx4*)(bl + 16 + q * 4);
        }

        float dtv = b2f(dt_c);
        float xv  = b2f(xs_c);
        float bx = dtv * xv;
        float aa[DS];
        if (fast) {
            pow_tree(__expf(dtv * ad0), aa);
        } else {
#pragma unroll
            for (int s = 0; s < DS; s++) aa[s] = __expf(dtv * adl[s]);
        }
        float y0 = 0.f, y1 = 0.f, y2 = 0.f, y3 = 0.f;
#pragma unroll
        for (int q = 0; q < 4; q++) {
#pragma unroll
            for (int j = 0; j < 4; j++) {
                int s = q * 4 + j;
                h[s] = aa[s] * h[s] + bx * Bq[q][j];
            }
        }
#pragma unroll
        for (int j = 0; j < 4; j++) {
            y0 += h[j] * Cq[0][j];
            y1 += h[4 + j] * Cq[1][j];
            y2 += h[8 + j] * Cq[2][j];
            y3 += h[12 + j] * Cq[3][j];
        }
        float yt = ((y0 + y1) + (y2 + y3)) + Dd * xv;
        float zv = b2f(z_c);
        float g = zv / (1.f + __expf(-zv));
        yg_p[0] = f2b(yt * g);

        dt_c = dt_1; dt_1 = dt_2;
        xs_c = xs_1; xs_1 = xs_2;
        z_c  = z_1;  z_1  = z_2;
        dt_p += LDXZ; xs_p += DI; z_p += LDXZ; yg_p += DI;
    }
}

// =====================================================================
extern "C" void kernel_launch(void* const* d_in, const int* in_sizes, int n_in,
                              void* d_out, int out_size, void* d_ws, size_t ws_size,
                              hipStream_t stream)
{
    const float* x      = (const float*)d_in[0];
    const float* W_in   = (const float*)d_in[1];
    const float* conv_w = (const float*)d_in[2];
    const float* conv_b = (const float*)d_in[3];
    const float* A_log  = (const float*)d_in[4];
    const float* Dvec   = (const float*)d_in[5];
    const float* W_x    = (const float*)d_in[6];
    const float* W_dt   = (const float*)d_in[7];
    const float* b_dt   = (const float*)d_in[8];
    const float* W_out  = (const float*)d_in[9];

    // ---- workspace arena (bf16 u16 elements), ~133 MB total ----
    u16* ws = (u16*)d_ws;
    u16* xz    = ws;                 ws += (size_t)M * LDXZ;     // 67.1 MB
    u16* xs    = ws;                 ws += (size_t)M * DI;       // 33.55 MB (yg in-place)
    u16* xbf   = ws;                 ws += (size_t)M * DM;       // 16.78 MB
    u16* wibf  = ws;                 ws += (size_t)2 * DI * DM;  // 8.39 MB (reused as bcf+sdt)
    u16* wxp   = ws;                 ws += (size_t)NPAD * DI;    // 0.52 MB
    u16* wdtb  = ws;                 ws += (size_t)DI * DTR;     // 0.26 MB
    u16* woutb = ws;                 ws += (size_t)DM * DI;      // 4.19 MB
    u16* xdbl  = ws;                 ws += (size_t)M * NPAD;     // 2.10 MB (M*64 used + ctrs)
    float* part  = (float*)xbf;      // split-K partials (xbf dead after GEMM1)
    float* scr_h = (float*)xbf;      // scan h scratch (part dead after gemm3_redk)
    float* bcf   = (float*)wibf;     // 1.05 MB (wibf dead after GEMM1)
    float* sdt_g = bcf + (size_t)M * 32;   // 1.05 MB, inside wibf region
    u32* ctrs   = (u32*)(xdbl + (size_t)M * 64);  // 96 counters in xdbl slack

    // 0) merged operand prep (+ counter zeroing)
    {
        constexpr int NTOT = M * DM + 2 * DI * DM + NPAD * DI + DI * DTR + DM * DI;
        prep_all<<<NTOT / 256, 256, 0, stream>>>(
            x, W_in, W_x, W_dt, W_out, xbf, wibf, wxp, wdtb, woutb, ctrs);
    }

    // 1) xz = x @ W_in^T   (8192 x 4096, K=1024)
    gemm256<0><<<dim3(LDXZ / 256, M / 256), 512, 0, stream>>>(
        xbf, wibf, xz, DM, DM, DM, LDXZ);

    // 2) conv + silu -> xs
    conv_silu<<<M, 256, 0, stream>>>(xz, conv_w, conv_b, xs);

    // 3) x_dbl = xs @ wxp^T split-K x4 + fused last-block redk
    gemm3_redk<<<dim3(1, M / 128, 4), 256, 0, stream>>>(
        xs, wxp, part, xdbl, bcf, ctrs);

    // 4) dt = softplus(x_dbl[:, :64] @ W_dt^T + b_dt) -> xr half of xz
    gemm_bt<2><<<dim3(DI / 128, M / 128), 256, 0, stream>>>(
        xdbl, wdtb, xz, b_dt, DTR, 64, DTR, LDXZ);

    // 5) scan p1 + fused last-block p2
    scan_p1p2<<<dim3(DI / 256, Bb, NCHUNK), 256, 0, stream>>>(
        xz, xs, bcf, A_log, scr_h, sdt_g, ctrs + 64);

    // 6) scan p3
    scan_p3<<<dim3(DI / 256, Bb, NCHUNK), 256, 0, stream>>>(
        xz, xs, bcf, scr_h, A_log, Dvec, xs);

    // 7) out = yg @ W_out^T   (8192 x 1024, K=2048)
    gemm256n128<1><<<dim3(DM / 128, M / 256), 512, 0, stream>>>(
        xs, woutb, d_out, DI, DI, DI, DM);
}

// Round 7
// 481.297 us; speedup vs baseline: 1.4034x; 1.4034x over previous
//
#include <hip/hip_runtime.h>
#include <math.h>

typedef unsigned short u16;
typedef unsigned int u32;

// ---- problem constants ----
constexpr int Bb = 4, Ll = 2048, DM = 1024, DI = 2048, DS = 16, DTR = 64, KC = 4;
constexpr int M = Bb * Ll;            // 8192 rows
constexpr int NPAD = 128;             // padded x_dbl width (64 + 2*16 = 96 -> 128)
constexpr int NCHUNK = 32;            // scan chunks
constexpr int LC = Ll / NCHUNK;       // 64 steps per chunk
constexpr int LDXZ = 4096;            // xz row stride (xr|z interleaved)

// ---- bf16 helpers on raw u16 ----
__device__ __forceinline__ float b2f(u16 u) {
    return __uint_as_float(((u32)u) << 16);
}
__device__ __forceinline__ u16 f2b(float f) {
    u32 x = __float_as_uint(f);
    u32 r = (x + 0x7fffu + ((x >> 16) & 1u)) >> 16;   // round-to-nearest-even
    return (u16)r;
}

typedef __attribute__((ext_vector_type(8))) short short8;
typedef __attribute__((ext_vector_type(4))) short short4v;
typedef __attribute__((ext_vector_type(4))) float floatx4;

// async global->LDS, 16B per lane; LDS dest = wave-uniform base + lane*16
__device__ __forceinline__ void gload16(const u16* g, u16* l) {
    __builtin_amdgcn_global_load_lds(
        (const __attribute__((address_space(1))) void*)g,
        (__attribute__((address_space(3))) void*)l,
        16, 0, 0);
}

// a^(s+1) for s=0..15 from base a, tree form (15 muls, depth 4)
__device__ __forceinline__ void pow_tree(float a, float* aa) {
    float a2 = a * a, a4 = a2 * a2, a8 = a4 * a4;
    aa[0] = a;        aa[1] = a2;       aa[2] = a * a2;   aa[3] = a4;
    aa[4] = a * a4;   aa[5] = a2 * a4;  aa[6] = aa[2] * a4; aa[7] = a8;
    aa[8] = a * a8;   aa[9] = a2 * a8;  aa[10] = aa[2] * a8; aa[11] = a4 * a8;
    aa[12] = aa[4] * a8; aa[13] = aa[5] * a8; aa[14] = aa[6] * a8; aa[15] = a8 * a8;
}

// XCD-chunked bijective blockIdx swizzle (T1, m204-style).
template<int GX, int GY>
__device__ __forceinline__ void xcd_swizzle(int& bx, int& by) {
    const int bid = blockIdx.y * GX + blockIdx.x;
    const int xcd = bid & 7;
    const int i = bid >> 3;
    const int c_local = i >> 5;
    const int within = i & 31;
    const int lx = within & 7, ly = within >> 3;
    const int chunk = xcd + c_local * 8;
    constexpr int CXN = GX / 8;
    const int cx = chunk % CXN;
    const int cy = chunk / CXN;
    bx = cx * 8 + lx;
    by = cy * 4 + ly;
}

// =====================================================================
// Big-tile GEMM: 256x256 tile, 8 waves (2M x 4N), BK=32, 4-deep
// circular LDS buffer, one phase per K-tile, counted vmcnt(8),
// setprio, XCD swizzle.  846 TF @ K=1024 (R4) = catalog level (m248).
// OUTM: 0 = bf16 store, 1 = fp32 store.  Grid must be (16, 32).
// =====================================================================
template<int OUTM>
__global__ __launch_bounds__(512, 2) void gemm256(
    const u16* __restrict__ A, const u16* __restrict__ Bm,
    void* __restrict__ Cv,
    int K, int lda, int ldb, int ldc)
{
    __shared__ alignas(16) u16 ldsA[4][256 * 32];   // 64 KiB
    __shared__ alignas(16) u16 ldsB[4][256 * 32];   // 64 KiB

    int bx, by;
    xcd_swizzle<16, 32>(bx, by);

    const int lane = threadIdx.x & 63;
    const int wave = threadIdx.x >> 6;
    const int wr = wave >> 2;
    const int wc = wave & 3;
    const int m0 = by * 256;
    const int n0 = bx * 256;

    const int lrow = lane >> 2;
    const int skc  = (((lane & 3) + (lane >> 3)) & 3) * 8;
    const u16* pA = A  + (size_t)(m0 + wave * 32 + lrow) * lda + skc;
    const u16* pB = Bm + (size_t)(n0 + wave * 32 + lrow) * ldb + skc;
    const int ldst = wave * 1024;

    const int r16 = lane & 15;
    const int quad = lane >> 4;
    const int slot = (quad + 4 - ((r16 >> 1) & 3)) & 3;
    const int aoff = (wr * 128 + r16) * 32 + slot * 8;
    const int boff = (wc * 64  + r16) * 32 + slot * 8;

    const int NT = K >> 5;

    floatx4 acc[8][4] = {};

#pragma unroll
    for (int t = 0; t < 3; ++t) {
        gload16(pA + t * 32,            &ldsA[t][ldst]);
        gload16(pA + t * 32 + 16 * lda, &ldsA[t][ldst + 512]);
        gload16(pB + t * 32,            &ldsB[t][ldst]);
        gload16(pB + t * 32 + 16 * ldb, &ldsB[t][ldst + 512]);
    }
    asm volatile("s_waitcnt vmcnt(8)" ::: "memory");
    __builtin_amdgcn_sched_barrier(0);
    __builtin_amdgcn_s_barrier();

    for (int t = 0; t < NT; ++t) {
        const u16* la = &ldsA[t & 3][aoff];
        const u16* lb = &ldsB[t & 3][boff];
        short8 af[8], bf[4];
#pragma unroll
        for (int i = 0; i < 8; ++i) af[i] = *(const short8*)(la + i * 512);
#pragma unroll
        for (int j = 0; j < 4; ++j) bf[j] = *(const short8*)(lb + j * 512);
        if (t + 3 < NT) {
            const u16* sA = pA + (t + 3) * 32;
            const u16* sB = pB + (t + 3) * 32;
            u16* dA = &ldsA[(t + 3) & 3][ldst];
            u16* dB = &ldsB[(t + 3) & 3][ldst];
            gload16(sA, dA);
            gload16(sA + 16 * lda, dA + 512);
            gload16(sB, dB);
            gload16(sB + 16 * ldb, dB + 512);
        }
        __builtin_amdgcn_sched_barrier(0);
        __builtin_amdgcn_s_barrier();
        asm volatile("s_waitcnt lgkmcnt(0)" ::: "memory");
        __builtin_amdgcn_sched_barrier(0);
        __builtin_amdgcn_s_setprio(1);
#pragma unroll
        for (int i = 0; i < 8; ++i)
#pragma unroll
            for (int j = 0; j < 4; ++j)
                acc[i][j] = __builtin_amdgcn_mfma_f32_16x16x32_bf16(
                    af[i], bf[j], acc[i][j], 0, 0, 0);
        __builtin_amdgcn_s_setprio(0);
        if (t + 3 < NT)      asm volatile("s_waitcnt vmcnt(8)" ::: "memory");
        else if (t + 2 < NT) asm volatile("s_waitcnt vmcnt(4)" ::: "memory");
        else if (t + 1 < NT) asm volatile("s_waitcnt vmcnt(0)" ::: "memory");
        __builtin_amdgcn_sched_barrier(0);
        __builtin_amdgcn_s_barrier();
    }

    const int mw = m0 + wr * 128;
    const int nw = n0 + wc * 64;
    const int rb = quad * 4;
#pragma unroll
    for (int i = 0; i < 8; ++i) {
#pragma unroll
        for (int j = 0; j < 4; ++j) {
            const int n = nw + j * 16 + r16;
#pragma unroll
            for (int r = 0; r < 4; ++r) {
                const int m = mw + i * 16 + rb + r;
                float v = acc[i][j][r];
                if (OUTM == 1)
                    ((float*)Cv)[(size_t)m * ldc + n] = v;
                else
                    ((u16*)Cv)[(size_t)m * ldc + n] = f2b(v);
            }
        }
    }
}

// =====================================================================
// 256x128-tile variant for GEMM6 (N=1024).  3-deep circular buffer,
// 2 blocks/CU, XCD swizzle.  Grid must be (8, 32).
// =====================================================================
template<int OUTM>
__global__ __launch_bounds__(512, 4) void gemm256n128(
    const u16* __restrict__ A, const u16* __restrict__ Bm,
    void* __restrict__ Cv,
    int K, int lda, int ldb, int ldc)
{
    __shared__ alignas(16) u16 ldsA[3][256 * 32];   // 48 KiB
    __shared__ alignas(16) u16 ldsB[3][128 * 32];   // 24 KiB

    int bx, by;
    xcd_swizzle<8, 32>(bx, by);

    const int lane = threadIdx.x & 63;
    const int wave = threadIdx.x >> 6;
    const int wr = wave >> 1;
    const int wc = wave & 1;
    const int m0 = by * 256;
    const int n0 = bx * 128;

    const int lrow = lane >> 2;
    const int skc  = (((lane & 3) + (lane >> 3)) & 3) * 8;
    const u16* pA = A  + (size_t)(m0 + wave * 32 + lrow) * lda + skc;
    const u16* pB = Bm + (size_t)(n0 + wave * 16 + lrow) * ldb + skc;
    const int ldstA = wave * 1024;
    const int ldstB = wave * 512;

    const int r16 = lane & 15;
    const int quad = lane >> 4;
    const int slot = (quad + 4 - ((r16 >> 1) & 3)) & 3;
    const int aoff = (wr * 64 + r16) * 32 + slot * 8;
    const int boff = (wc * 64 + r16) * 32 + slot * 8;

    const int NT = K >> 5;

    floatx4 acc[4][4] = {};

#pragma unroll
    for (int t = 0; t < 2; ++t) {
        gload16(pA + t * 32,            &ldsA[t][ldstA]);
        gload16(pA + t * 32 + 16 * lda, &ldsA[t][ldstA + 512]);
        gload16(pB + t * 32,            &ldsB[t][ldstB]);
    }
    asm volatile("s_waitcnt vmcnt(3)" ::: "memory");
    __builtin_amdgcn_sched_barrier(0);
    __builtin_amdgcn_s_barrier();

    int bc = 0, bs = 2;
    for (int t = 0; t < NT; ++t) {
        const u16* la = &ldsA[bc][aoff];
        const u16* lb = &ldsB[bc][boff];
        short8 af[4], bf[4];
#pragma unroll
        for (int i = 0; i < 4; ++i) af[i] = *(const short8*)(la + i * 512);
#pragma unroll
        for (int j = 0; j < 4; ++j) bf[j] = *(const short8*)(lb + j * 512);
        if (t + 2 < NT) {
            const u16* sa = pA + (t + 2) * 32;
            u16* da = &ldsA[bs][ldstA];
            gload16(sa, da);
            gload16(sa + 16 * lda, da + 512);
            gload16(pB + (t + 2) * 32, &ldsB[bs][ldstB]);
        }
        __builtin_amdgcn_sched_barrier(0);
        __builtin_amdgcn_s_barrier();
        asm volatile("s_waitcnt lgkmcnt(0)" ::: "memory");
        __builtin_amdgcn_sched_barrier(0);
        __builtin_amdgcn_s_setprio(1);
#pragma unroll
        for (int i = 0; i < 4; ++i)
#pragma unroll
            for (int j = 0; j < 4; ++j)
                acc[i][j] = __builtin_amdgcn_mfma_f32_16x16x32_bf16(
                    af[i], bf[j], acc[i][j], 0, 0, 0);
        __builtin_amdgcn_s_setprio(0);
        if (t + 2 < NT)      asm volatile("s_waitcnt vmcnt(3)" ::: "memory");
        else if (t + 1 < NT) asm volatile("s_waitcnt vmcnt(0)" ::: "memory");
        __builtin_amdgcn_sched_barrier(0);
        __builtin_amdgcn_s_barrier();
        bc = (bc == 2) ? 0 : bc + 1;
        bs = (bs == 2) ? 0 : bs + 1;
    }

    const int mw = m0 + wr * 64;
    const int nw = n0 + wc * 64;
    const int rb = quad * 4;
#pragma unroll
    for (int i = 0; i < 4; ++i) {
#pragma unroll
        for (int j = 0; j < 4; ++j) {
            const int n = nw + j * 16 + r16;
#pragma unroll
            for (int r = 0; r < 4; ++r) {
                const int m = mw + i * 16 + rb + r;
                float v = acc[i][j][r];
                if (OUTM == 1)
                    ((float*)Cv)[(size_t)m * ldc + n] = v;
                else
                    ((u16*)Cv)[(size_t)m * ldc + n] = f2b(v);
            }
        }
    }
}

// =====================================================================
// m97-structure GEMM, used for GEMM3 (OUTM=4: split-K fp32 partials).
// n >= 96 stores skipped (zero-pad cols, nothing reads them).
// =====================================================================
template<int OUTM>
__global__ __launch_bounds__(256) void gemm_bt(
    const u16* __restrict__ A, const u16* __restrict__ Bm,
    void* __restrict__ Cv, const float* __restrict__ bias,
    int K, int lda, int ldb, int ldc)
{
    __shared__ alignas(16) u16 ldsA[128 * 32];
    __shared__ alignas(16) u16 ldsB[128 * 32];

    const int lane = threadIdx.x & 63;
    const int wave = threadIdx.x >> 6;
    const int wr = wave >> 1, wc = wave & 1;
    const int m0 = blockIdx.y * 128;
    const int n0 = blockIdx.x * 128;
    const int koff = (OUTM == 4) ? blockIdx.z * K : 0;

    const int srow = wave * 32 + (lane >> 2);
    const int skc  = (((lane & 3) + (lane >> 3)) & 3) * 8;
    const u16* Ag = A + (size_t)(m0 + srow) * lda + skc + koff;
    const u16* Bg = Bm + (size_t)(n0 + srow) * ldb + skc + koff;
    u16* lA = &ldsA[wave * 1024];
    u16* lB = &ldsB[wave * 1024];

    const int r16 = lane & 15;
    const int quad = lane >> 4;
    const int slot = (quad + 4 - ((r16 >> 1) & 3)) & 3;
    const u16* arow = &ldsA[(wr * 64 + r16) * 32 + slot * 8];
    const u16* brow = &ldsB[(wc * 64 + r16) * 32 + slot * 8];

    floatx4 acc[4][4] = {};

    for (int k0 = 0; k0 < K; k0 += 32) {
        gload16(Ag + k0,                    lA);
        gload16(Ag + k0 + (size_t)16 * lda, lA + 512);
        gload16(Bg + k0,                    lB);
        gload16(Bg + k0 + (size_t)16 * ldb, lB + 512);
        __syncthreads();

        short8 af[4], bf[4];
#pragma unroll
        for (int i = 0; i < 4; i++) af[i] = *(const short8*)(arow + i * 16 * 32);
#pragma unroll
        for (int j = 0; j < 4; j++) bf[j] = *(const short8*)(brow + j * 16 * 32);
#pragma unroll
        for (int i = 0; i < 4; i++)
#pragma unroll
            for (int j = 0; j < 4; j++)
                acc[i][j] = __builtin_amdgcn_mfma_f32_16x16x32_bf16(
                    af[i], bf[j], acc[i][j], 0, 0, 0);
        __syncthreads();
    }

    const int mw = m0 + wr * 64;
    const int nw = n0 + wc * 64;
    const int rb = quad * 4;
#pragma unroll
    for (int i = 0; i < 4; i++) {
#pragma unroll
        for (int j = 0; j < 4; j++) {
            const int n = nw + j * 16 + r16;
            if (OUTM == 4 && n >= 96) continue;   // dead zero-pad cols
#pragma unroll
            for (int r = 0; r < 4; r++) {
                const int m = mw + i * 16 + rb + r;
                float v = acc[i][j][r];
                if (OUTM == 4)
                    ((float*)Cv)[((size_t)blockIdx.z * M + m) * ldc + n] = v;
                else if (OUTM == 1)
                    ((float*)Cv)[(size_t)m * ldc + n] = v;
                else
                    ((u16*)Cv)[(size_t)m * ldc + n] = f2b(v);
            }
        }
    }
}

// =====================================================================
// GEMM4 with FUSED split-K reduce (no sync, no fence): each block
// (128 rows x 128 dt-cols, K=64) reduces the 4 fp32 partials itself
// into a bf16 XOR-swizzled LDS A-tile, reg-stages B, runs 32 MFMAs,
// softplus(+bias) epilogue -> xr half of xz.  bx==0 blocks also emit
// the fp32 bcf sideband (partial cols 64..95).  Zero cross-block deps.
// Grid (16, 64).
// =====================================================================
__global__ __launch_bounds__(256) void gemm4_fused(
    const float* __restrict__ part, const u16* __restrict__ wdtb,
    const float* __restrict__ b_dt, u16* __restrict__ xz,
    float* __restrict__ bcf)
{
    __shared__ alignas(16) u16 lA[128 * 64];   // 16 KiB
    __shared__ alignas(16) u16 lB[128 * 64];   // 16 KiB

    const int tid = threadIdx.x;
    const int m0 = blockIdx.y * 128;
    const int n0 = blockIdx.x * 128;

    // ---- stage A: reduce 4 fp32 partials -> bf16, XOR-swizzle g^=(r&7) ----
    {
        const int r = tid >> 1;              // 0..127
        const int hh = tid & 1;              // 32-col half
        const size_t stride = (size_t)M * NPAD;
        const float* p = part + (size_t)(m0 + r) * NPAD + hh * 32;
#pragma unroll
        for (int cg = 0; cg < 4; cg++) {
            floatx4 s0 = *(const floatx4*)(p + cg * 8)
                       + *(const floatx4*)(p + stride + cg * 8)
                       + *(const floatx4*)(p + 2 * stride + cg * 8)
                       + *(const floatx4*)(p + 3 * stride + cg * 8);
            floatx4 s1 = *(const floatx4*)(p + cg * 8 + 4)
                       + *(const floatx4*)(p + stride + cg * 8 + 4)
                       + *(const floatx4*)(p + 2 * stride + cg * 8 + 4)
                       + *(const floatx4*)(p + 3 * stride + cg * 8 + 4);
            short8 ob;
#pragma unroll
            for (int j = 0; j < 4; j++) {
                ob[j]     = (short)f2b(s0[j]);
                ob[4 + j] = (short)f2b(s1[j]);
            }
            const int g = hh * 4 + cg;
            *(short8*)(&lA[r * 64 + ((g ^ (r & 7)) * 8)]) = ob;
        }
    }
    // ---- stage B: wdtb rows n0..n0+127 (bf16), same swizzle ----
    {
        const int rn = tid >> 1;
        const int hh = tid & 1;
        const u16* src = wdtb + (size_t)(n0 + rn) * 64 + hh * 32;
#pragma unroll
        for (int cg = 0; cg < 4; cg++) {
            short8 wv = *(const short8*)(src + cg * 8);
            const int g = hh * 4 + cg;
            *(short8*)(&lB[rn * 64 + ((g ^ (rn & 7)) * 8)]) = wv;
        }
    }
    // ---- bcf sideband (partial cols 64..95), bx==0 blocks only ----
    if (blockIdx.x == 0) {
        const int r = tid >> 1;
        const int hh = tid & 1;              // 16-col half
        const size_t stride = (size_t)M * NPAD;
        const float* p = part + (size_t)(m0 + r) * NPAD + 64 + hh * 16;
        float* q = bcf + (size_t)(m0 + r) * 32 + hh * 16;
#pragma unroll
        for (int g = 0; g < 4; g++) {
            floatx4 s = *(const floatx4*)(p + g * 4)
                      + *(const floatx4*)(p + stride + g * 4)
                      + *(const floatx4*)(p + 2 * stride + g * 4)
                      + *(const floatx4*)(p + 3 * stride + g * 4);
            *(floatx4*)(q + g * 4) = s;
        }
    }
    __syncthreads();

    const int lane = tid & 63;
    const int wave = tid >> 6;
    const int wr = wave >> 1, wc = wave & 1;
    const int r16 = lane & 15;
    const int quad = lane >> 4;

    floatx4 acc[4][4] = {};
#pragma unroll
    for (int ks = 0; ks < 2; ks++) {
        short8 af[4], bf[4];
        const int g = ks * 4 + quad;         // logical k-chunk (quad*8 within k-tile)
#pragma unroll
        for (int i = 0; i < 4; i++) {
            const int row = wr * 64 + i * 16 + r16;
            af[i] = *(const short8*)(&lA[row * 64 + ((g ^ (row & 7)) * 8)]);
        }
#pragma unroll
        for (int j = 0; j < 4; j++) {
            const int row = wc * 64 + j * 16 + r16;
            bf[j] = *(const short8*)(&lB[row * 64 + ((g ^ (row & 7)) * 8)]);
        }
#pragma unroll
        for (int i = 0; i < 4; i++)
#pragma unroll
            for (int j = 0; j < 4; j++)
                acc[i][j] = __builtin_amdgcn_mfma_f32_16x16x32_bf16(
                    af[i], bf[j], acc[i][j], 0, 0, 0);
    }

    // epilogue: softplus(acc + b_dt[n]) -> bf16 dt into xr half of xz
    const int mw = m0 + wr * 64;
    const int nw = n0 + wc * 64;
    const int rb = quad * 4;
#pragma unroll
    for (int i = 0; i < 4; i++) {
#pragma unroll
        for (int j = 0; j < 4; j++) {
            const int n = nw + j * 16 + r16;
            const float bb = b_dt[n];
#pragma unroll
            for (int r = 0; r < 4; r++) {
                const int m = mw + i * 16 + rb + r;
                float v = acc[i][j][r] + bb;
                v = (v > 20.f) ? v : log1pf(__expf(v));
                xz[(size_t)m * LDXZ + n] = f2b(v);
            }
        }
    }
}

// =====================================================================
// merged operand prep: x cvt | W_in cvt | W_x pad | W_dt cvt | W_out cvt
// =====================================================================
__global__ __launch_bounds__(256) void prep_all(
    const float* __restrict__ x, const float* __restrict__ W_in,
    const float* __restrict__ W_x, const float* __restrict__ W_dt,
    const float* __restrict__ W_out,
    u16* __restrict__ xbf, u16* __restrict__ wibf, u16* __restrict__ wxp,
    u16* __restrict__ wdtb, u16* __restrict__ woutb)
{
    constexpr int N0 = M * DM;
    constexpr int N1 = 2 * DI * DM;
    constexpr int N2 = NPAD * DI;
    constexpr int N3 = DI * DTR;
    int idx = blockIdx.x * blockDim.x + threadIdx.x;
    if (idx < N0) {
        xbf[idx] = f2b(x[idx]);
        return;
    }
    idx -= N0;
    if (idx < N1) {
        wibf[idx] = f2b(W_in[idx]);
    } else if (idx < N1 + N2) {
        int i = idx - N1;
        int r = i >> 11, c = i & 2047;
        wxp[i] = (r < 96) ? f2b(W_x[r * 2048 + c]) : (u16)0;
    } else if (idx < N1 + N2 + N3) {
        int i = idx - N1 - N2;
        wdtb[i] = f2b(W_dt[i]);
    } else {
        int i = idx - N1 - N2 - N3;
        woutb[i] = f2b(W_out[i]);
    }
}

// =====================================================================
// Depthwise causal conv (K=4) + SiLU, vectorized.
// =====================================================================
__global__ __launch_bounds__(256) void conv_silu(
    const u16* __restrict__ xz, const float* __restrict__ conv_w,
    const float* __restrict__ conv_b, u16* __restrict__ xs)
{
    const int m = blockIdx.x;
    const int d0 = threadIdx.x * 8;
    const int l = m & (Ll - 1);

    float acc[8];
    {
        floatx4 cb0 = *(const floatx4*)(conv_b + d0);
        floatx4 cb1 = *(const floatx4*)(conv_b + d0 + 4);
#pragma unroll
        for (int j = 0; j < 4; j++) { acc[j] = cb0[j]; acc[4 + j] = cb1[j]; }
    }
    float w[8][KC];
#pragma unroll
    for (int jd = 0; jd < 8; jd++) {
        floatx4 wv = *(const floatx4*)(conv_w + (d0 + jd) * KC);
#pragma unroll
        for (int k = 0; k < KC; k++) w[jd][k] = wv[k];
    }
#pragma unroll
    for (int k = 0; k < KC; k++) {
        int li = l - (KC - 1) + k;
        if (li >= 0) {
            short8 xv = *(const short8*)(xz + (size_t)(m - (KC - 1) + k) * LDXZ + d0);
#pragma unroll
            for (int jd = 0; jd < 8; jd++)
                acc[jd] += b2f((u16)xv[jd]) * w[jd][k];
        }
    }
    short8 o;
#pragma unroll
    for (int jd = 0; jd < 8; jd++) {
        float s = acc[jd] / (1.f + __expf(-acc[jd]));
        o[jd] = (short)f2b(s);
    }
    *(short8*)(xs + (size_t)m * DI + d0) = o;
}

// =====================================================================
// Chunked selective scan, NCHUNK=32 (1024 blocks).  Inter-chunk state
// compressed via P_s = exp(a_s * sum(dt)); p1 stores h_end + sdt; p2
// reconstructs P and runs in-place.
// =====================================================================
__global__ __launch_bounds__(256) void scan_p1(
    const u16* __restrict__ xzdt, const u16* __restrict__ xs,
    const float* __restrict__ bcf, const float* __restrict__ A_log,
    float* __restrict__ scr_h, float* __restrict__ sdt_g)
{
    __shared__ alignas(16) float bcs[LC * 32];   // 8 KB

    const int d = blockIdx.x * 256 + threadIdx.x;
    const int b = blockIdx.y;
    const int c = blockIdx.z;
    const int m0 = b * Ll + c * LC;

    {
        const float* bc_g = bcf + (size_t)m0 * 32;
#pragma unroll
        for (int j = 0; j < 2; j++) {
            int idx = j * 1024 + threadIdx.x * 4;
            *(floatx4*)(bcs + idx) = *(const floatx4*)(bc_g + idx);
        }
    }

    const float ad0 = -__expf(A_log[0]);
    float adl[DS];
    bool fast = true;
#pragma unroll
    for (int s = 0; s < DS; s++) {
        float av = -__expf(A_log[s]);
        adl[s] = av;
        float kr = (float)(s + 1);
        if (fabsf(av / ad0 - kr) > 1e-4f * kr) fast = false;
    }

    const u16* dt_p = xzdt + (size_t)m0 * LDXZ + d;
    const u16* xs_p = xs + (size_t)m0 * DI + d;

    float h[DS] = {};
    float sdt = 0.f;

    __syncthreads();

    u16 dt_c = dt_p[0],     xs_c = xs_p[0];
    u16 dt_1 = dt_p[LDXZ],  xs_1 = xs_p[DI];

    if (fast) {
        for (int l = 0; l < LC; l++) {
            u16 dt_2 = dt_p[2 * LDXZ];
            u16 xs_2 = xs_p[2 * DI];
            const float* bl = bcs + l * 32;
            floatx4 B0 = *(const floatx4*)(bl);
            floatx4 B1 = *(const floatx4*)(bl + 4);
            floatx4 B2 = *(const floatx4*)(bl + 8);
            floatx4 B3 = *(const floatx4*)(bl + 12);

            float dtv = b2f(dt_c);
            float xv  = b2f(xs_c);
            float bx = dtv * xv;
            sdt += dtv;
            float aa[DS];
            pow_tree(__expf(dtv * ad0), aa);
#pragma unroll
            for (int s = 0; s < DS; s++) {
                float Bv = (s < 4) ? B0[s] : (s < 8) ? B1[s - 4]
                         : (s < 12) ? B2[s - 8] : B3[s - 12];
                h[s] = aa[s] * h[s] + bx * Bv;
            }
            dt_c = dt_1; dt_1 = dt_2; xs_c = xs_1; xs_1 = xs_2;
            dt_p += LDXZ; xs_p += DI;
        }
    } else {
        for (int l = 0; l < LC; l++) {
            u16 dt_2 = dt_p[2 * LDXZ];
            u16 xs_2 = xs_p[2 * DI];
            const float* bl = bcs + l * 32;
            floatx4 B0 = *(const floatx4*)(bl);
            floatx4 B1 = *(const floatx4*)(bl + 4);
            floatx4 B2 = *(const floatx4*)(bl + 8);
            floatx4 B3 = *(const floatx4*)(bl + 12);

            float dtv = b2f(dt_c);
            float xv  = b2f(xs_c);
            float bx = dtv * xv;
            sdt += dtv;
#pragma unroll
            for (int s = 0; s < DS; s++) {
                float Bv = (s < 4) ? B0[s] : (s < 8) ? B1[s - 4]
                         : (s < 12) ? B2[s - 8] : B3[s - 12];
                float a = __expf(dtv * adl[s]);
                h[s] = a * h[s] + bx * Bv;
            }
            dt_c = dt_1; dt_1 = dt_2; xs_c = xs_1; xs_1 = xs_2;
            dt_p += LDXZ; xs_p += DI;
        }
    }

    const size_t base = ((size_t)(b * NCHUNK + c) * DI + d) * DS;
#pragma unroll
    for (int s = 0; s < DS; s += 4) {
        floatx4 hv = {h[s], h[s+1], h[s+2], h[s+3]};
        *(floatx4*)(scr_h + base + s) = hv;
    }
    sdt_g[(size_t)(b * NCHUNK + c) * DI + d] = sdt;
}

// in-place chunk-prefix: scr_h holds h_end on entry, h_in on exit
__global__ __launch_bounds__(256) void scan_p2(
    float* __restrict__ scr_h, const float* __restrict__ sdt_g,
    const float* __restrict__ A_log)
{
    const int t = blockIdx.x * 256 + threadIdx.x;   // (b, d, s)
    const int s = t & 15;
    const int d = (t >> 4) & (DI - 1);
    const int b = t >> 15;
    const float adl = -__expf(A_log[s]);

    float hin = 0.f;
    for (int c0 = 0; c0 < NCHUNK; c0 += 8) {
        float he[8], P[8];
#pragma unroll
        for (int j = 0; j < 8; j++) {
            const size_t base = ((size_t)(b * NCHUNK + c0 + j) * DI + d) * DS + s;
            he[j] = scr_h[base];
            P[j] = adl * sdt_g[(size_t)(b * NCHUNK + c0 + j) * DI + d];
        }
#pragma unroll
        for (int j = 0; j < 8; j++) P[j] = __expf(P[j]);
#pragma unroll
        for (int j = 0; j < 8; j++) {
            const size_t base = ((size_t)(b * NCHUNK + c0 + j) * DI + d) * DS + s;
            scr_h[base] = hin;
            hin = P[j] * hin + he[j];
        }
    }
}

__global__ __launch_bounds__(256) void scan_p3(
    const u16* __restrict__ xz, const u16* xs, const float* __restrict__ bcf,
    const float* __restrict__ scr_hin, const float* __restrict__ A_log,
    const float* __restrict__ Dvec, u16* yg)
{
    __shared__ alignas(16) float bcs[LC * 32];   // 8 KB

    const int d = blockIdx.x * 256 + threadIdx.x;
    const int b = blockIdx.y;
    const int c = blockIdx.z;
    const int m0 = b * Ll + c * LC;

    {
        const float* bc_g = bcf + (size_t)m0 * 32;
#pragma unroll
        for (int j = 0; j < 2; j++) {
            int idx = j * 1024 + threadIdx.x * 4;
            *(floatx4*)(bcs + idx) = *(const floatx4*)(bc_g + idx);
        }
    }

    const float ad0 = -__expf(A_log[0]);
    float adl[DS];
    bool fast = true;
#pragma unroll
    for (int s = 0; s < DS; s++) {
        float av = -__expf(A_log[s]);
        adl[s] = av;
        float kr = (float)(s + 1);
        if (fabsf(av / ad0 - kr) > 1e-4f * kr) fast = false;
    }
    const float Dd = Dvec[d];

    const u16* dt_p = xz + (size_t)m0 * LDXZ + d;
    const u16* z_p  = xz + (size_t)m0 * LDXZ + 2048 + d;
    const u16* xs_p = xs + (size_t)m0 * DI + d;
    u16* yg_p = yg + (size_t)m0 * DI + d;

    float h[DS];
    const size_t base = ((size_t)(b * NCHUNK + c) * DI + d) * DS;
#pragma unroll
    for (int s = 0; s < DS; s += 4) {
        floatx4 hv = *(const floatx4*)(scr_hin + base + s);
        h[s] = hv[0]; h[s+1] = hv[1]; h[s+2] = hv[2]; h[s+3] = hv[3];
    }

    __syncthreads();

    u16 dt_c = dt_p[0],    dt_1 = dt_p[LDXZ];
    u16 xs_c = xs_p[0],    xs_1 = xs_p[DI];
    u16 z_c  = z_p[0],     z_1  = z_p[LDXZ];

    for (int l = 0; l < LC; l++) {
        u16 dt_2 = dt_p[2 * LDXZ];
        u16 xs_2 = xs_p[2 * DI];
        u16 z_2  = z_p[2 * LDXZ];
        const float* bl = bcs + l * 32;
        floatx4 Bq[4], Cq[4];
#pragma unroll
        for (int q = 0; q < 4; q++) {
            Bq[q] = *(const floatx4*)(bl + q * 4);
            Cq[q] = *(const floatx4*)(bl + 16 + q * 4);
        }

        float dtv = b2f(dt_c);
        float xv  = b2f(xs_c);
        float bx = dtv * xv;
        float aa[DS];
        if (fast) {
            pow_tree(__expf(dtv * ad0), aa);
        } else {
#pragma unroll
            for (int s = 0; s < DS; s++) aa[s] = __expf(dtv * adl[s]);
        }
        float y0 = 0.f, y1 = 0.f, y2 = 0.f, y3 = 0.f;
#pragma unroll
        for (int q = 0; q < 4; q++) {
#pragma unroll
            for (int j = 0; j < 4; j++) {
                int s = q * 4 + j;
                h[s] = aa[s] * h[s] + bx * Bq[q][j];
            }
        }
#pragma unroll
        for (int j = 0; j < 4; j++) {
            y0 += h[j] * Cq[0][j];
            y1 += h[4 + j] * Cq[1][j];
            y2 += h[8 + j] * Cq[2][j];
            y3 += h[12 + j] * Cq[3][j];
        }
        float yt = ((y0 + y1) + (y2 + y3)) + Dd * xv;
        float zv = b2f(z_c);
        float g = zv / (1.f + __expf(-zv));
        yg_p[0] = f2b(yt * g);

        dt_c = dt_1; dt_1 = dt_2;
        xs_c = xs_1; xs_1 = xs_2;
        z_c  = z_1;  z_1  = z_2;
        dt_p += LDXZ; xs_p += DI; z_p += LDXZ; yg_p += DI;
    }
}

// =====================================================================
extern "C" void kernel_launch(void* const* d_in, const int* in_sizes, int n_in,
                              void* d_out, int out_size, void* d_ws, size_t ws_size,
                              hipStream_t stream)
{
    const float* x      = (const float*)d_in[0];
    const float* W_in   = (const float*)d_in[1];
    const float* conv_w = (const float*)d_in[2];
    const float* conv_b = (const float*)d_in[3];
    const float* A_log  = (const float*)d_in[4];
    const float* Dvec   = (const float*)d_in[5];
    const float* W_x    = (const float*)d_in[6];
    const float* W_dt   = (const float*)d_in[7];
    const float* b_dt   = (const float*)d_in[8];
    const float* W_out  = (const float*)d_in[9];

    // ---- workspace arena (bf16 u16 elements), ~133 MB total ----
    u16* ws = (u16*)d_ws;
    u16* xz    = ws;                 ws += (size_t)M * LDXZ;     // 67.1 MB
    u16* xs    = ws;                 ws += (size_t)M * DI;       // 33.55 MB (yg in-place)
    u16* xbf   = ws;                 ws += (size_t)M * DM;       // 16.78 MB
    u16* wibf  = ws;                 ws += (size_t)2 * DI * DM;  // 8.39 MB (reused as bcf+sdt)
    u16* wxp   = ws;                 ws += (size_t)NPAD * DI;    // 0.52 MB
    u16* wdtb  = ws;                 ws += (size_t)DI * DTR;     // 0.26 MB
    u16* woutb = ws;                 ws += (size_t)DM * DI;      // 4.19 MB
    u16* xdbl  = ws;                 ws += (size_t)M * NPAD;     // 2.10 MB (unused slack)
    float* part  = (float*)xbf;      // split-K partials (xbf dead after GEMM1)
    float* scr_h = (float*)xbf;      // scan h scratch (part dead after gemm4_fused)
    float* bcf   = (float*)wibf;     // 1.05 MB (wibf dead after GEMM1)
    float* sdt_g = bcf + (size_t)M * 32;   // 1.05 MB, inside wibf region
    (void)xdbl;

    // 0) merged operand prep
    {
        constexpr int NTOT = M * DM + 2 * DI * DM + NPAD * DI + DI * DTR + DM * DI;
        prep_all<<<NTOT / 256, 256, 0, stream>>>(
            x, W_in, W_x, W_dt, W_out, xbf, wibf, wxp, wdtb, woutb);
    }

    // 1) xz = x @ W_in^T   (8192 x 4096, K=1024)
    gemm256<0><<<dim3(LDXZ / 256, M / 256), 512, 0, stream>>>(
        xbf, wibf, xz, DM, DM, DM, LDXZ);

    // 2) conv + silu -> xs
    conv_silu<<<M, 256, 0, stream>>>(xz, conv_w, conv_b, xs);

    // 3) x_dbl partials = xs @ wxp^T, split-K x4 (cols 0..95 only)
    gemm_bt<4><<<dim3(1, M / 128, 4), 256, 0, stream>>>(
        xs, wxp, part, nullptr, DI / 4, DI, DI, NPAD);

    // 4) dt = softplus(reduce(part) @ W_dt^T + b_dt) + bcf sideband, fused
    gemm4_fused<<<dim3(DI / 128, M / 128), 256, 0, stream>>>(
        part, wdtb, b_dt, xz, bcf);

    // 5) chunked scan
    scan_p1<<<dim3(DI / 256, Bb, NCHUNK), 256, 0, stream>>>(
        xz, xs, bcf, A_log, scr_h, sdt_g);
    scan_p2<<<(Bb * DI * DS) / 256, 256, 0, stream>>>(scr_h, sdt_g, A_log);
    scan_p3<<<dim3(DI / 256, Bb, NCHUNK), 256, 0, stream>>>(
        xz, xs, bcf, scr_h, A_log, Dvec, xs);

    // 6) out = yg @ W_out^T   (8192 x 1024, K=2048)
    gemm256n128<1><<<dim3(DM / 128, M / 256), 512, 0, stream>>>(
        xs, woutb, d_out, DI, DI, DI, DM);
}

// Round 8
// 415.494 us; speedup vs baseline: 1.6257x; 1.1584x over previous
//
#include <hip/hip_runtime.h>
#include <math.h>

typedef unsigned short u16;
typedef unsigned int u32;

// ---- problem constants ----
constexpr int Bb = 4, Ll = 2048, DM = 1024, DI = 2048, DS = 16, DTR = 64, KC = 4;
constexpr int M = Bb * Ll;            // 8192 rows
constexpr int NPAD = 128;             // padded x_dbl width (64 + 2*16 = 96 -> 128)
constexpr int NCHUNK = 32;            // scan chunks
constexpr int LC = Ll / NCHUNK;       // 64 steps per chunk
constexpr int LDXZ = 4096;            // xz row stride (xr|z interleaved)

// ---- bf16 helpers on raw u16 ----
__device__ __forceinline__ float b2f(u16 u) {
    return __uint_as_float(((u32)u) << 16);
}
__device__ __forceinline__ u16 f2b(float f) {
    u32 x = __float_as_uint(f);
    u32 r = (x + 0x7fffu + ((x >> 16) & 1u)) >> 16;   // round-to-nearest-even
    return (u16)r;
}
// fast softplus: v_exp_f32 + v_log_f32 (~8 VALU ops) instead of the
// OCML log1pf libcall (R7 finding: log1pf epilogue was a ~60us VALU hog).
// bf16 output tolerance (4.6e-2) >> the ~1e-7 accuracy difference.
__device__ __forceinline__ float softplus_fast(float v) {
    return (v > 20.f) ? v : __logf(1.f + __expf(v));
}

typedef __attribute__((ext_vector_type(8))) short short8;
typedef __attribute__((ext_vector_type(4))) short short4v;
typedef __attribute__((ext_vector_type(4))) float floatx4;

// async global->LDS, 16B per lane; LDS dest = wave-uniform base + lane*16
__device__ __forceinline__ void gload16(const u16* g, u16* l) {
    __builtin_amdgcn_global_load_lds(
        (const __attribute__((address_space(1))) void*)g,
        (__attribute__((address_space(3))) void*)l,
        16, 0, 0);
}

// a^(s+1) for s=0..15 from base a, tree form (15 muls, depth 4)
__device__ __forceinline__ void pow_tree(float a, float* aa) {
    float a2 = a * a, a4 = a2 * a2, a8 = a4 * a4;
    aa[0] = a;        aa[1] = a2;       aa[2] = a * a2;   aa[3] = a4;
    aa[4] = a * a4;   aa[5] = a2 * a4;  aa[6] = aa[2] * a4; aa[7] = a8;
    aa[8] = a * a8;   aa[9] = a2 * a8;  aa[10] = aa[2] * a8; aa[11] = a4 * a8;
    aa[12] = aa[4] * a8; aa[13] = aa[5] * a8; aa[14] = aa[6] * a8; aa[15] = a8 * a8;
}

// XCD-chunked bijective blockIdx swizzle (T1, m204-style).
template<int GX, int GY>
__device__ __forceinline__ void xcd_swizzle(int& bx, int& by) {
    const int bid = blockIdx.y * GX + blockIdx.x;
    const int xcd = bid & 7;
    const int i = bid >> 3;
    const int c_local = i >> 5;
    const int within = i & 31;
    const int lx = within & 7, ly = within >> 3;
    const int chunk = xcd + c_local * 8;
    constexpr int CXN = GX / 8;
    const int cx = chunk % CXN;
    const int cy = chunk / CXN;
    bx = cx * 8 + lx;
    by = cy * 4 + ly;
}

// =====================================================================
// Big-tile GEMM: 256x256 tile, 8 waves (2M x 4N), BK=32, 4-deep
// circular LDS buffer, one phase per K-tile, counted vmcnt(8),
// setprio, XCD swizzle.  846 TF @ K=1024 (R4) = catalog level (m248).
// OUTM: 0 = bf16 store, 1 = fp32 store.  Grid must be (16, 32).
// =====================================================================
template<int OUTM>
__global__ __launch_bounds__(512, 2) void gemm256(
    const u16* __restrict__ A, const u16* __restrict__ Bm,
    void* __restrict__ Cv,
    int K, int lda, int ldb, int ldc)
{
    __shared__ alignas(16) u16 ldsA[4][256 * 32];   // 64 KiB
    __shared__ alignas(16) u16 ldsB[4][256 * 32];   // 64 KiB

    int bx, by;
    xcd_swizzle<16, 32>(bx, by);

    const int lane = threadIdx.x & 63;
    const int wave = threadIdx.x >> 6;
    const int wr = wave >> 2;
    const int wc = wave & 3;
    const int m0 = by * 256;
    const int n0 = bx * 256;

    const int lrow = lane >> 2;
    const int skc  = (((lane & 3) + (lane >> 3)) & 3) * 8;
    const u16* pA = A  + (size_t)(m0 + wave * 32 + lrow) * lda + skc;
    const u16* pB = Bm + (size_t)(n0 + wave * 32 + lrow) * ldb + skc;
    const int ldst = wave * 1024;

    const int r16 = lane & 15;
    const int quad = lane >> 4;
    const int slot = (quad + 4 - ((r16 >> 1) & 3)) & 3;
    const int aoff = (wr * 128 + r16) * 32 + slot * 8;
    const int boff = (wc * 64  + r16) * 32 + slot * 8;

    const int NT = K >> 5;

    floatx4 acc[8][4] = {};

#pragma unroll
    for (int t = 0; t < 3; ++t) {
        gload16(pA + t * 32,            &ldsA[t][ldst]);
        gload16(pA + t * 32 + 16 * lda, &ldsA[t][ldst + 512]);
        gload16(pB + t * 32,            &ldsB[t][ldst]);
        gload16(pB + t * 32 + 16 * ldb, &ldsB[t][ldst + 512]);
    }
    asm volatile("s_waitcnt vmcnt(8)" ::: "memory");
    __builtin_amdgcn_sched_barrier(0);
    __builtin_amdgcn_s_barrier();

    for (int t = 0; t < NT; ++t) {
        const u16* la = &ldsA[t & 3][aoff];
        const u16* lb = &ldsB[t & 3][boff];
        short8 af[8], bf[4];
#pragma unroll
        for (int i = 0; i < 8; ++i) af[i] = *(const short8*)(la + i * 512);
#pragma unroll
        for (int j = 0; j < 4; ++j) bf[j] = *(const short8*)(lb + j * 512);
        if (t + 3 < NT) {
            const u16* sA = pA + (t + 3) * 32;
            const u16* sB = pB + (t + 3) * 32;
            u16* dA = &ldsA[(t + 3) & 3][ldst];
            u16* dB = &ldsB[(t + 3) & 3][ldst];
            gload16(sA, dA);
            gload16(sA + 16 * lda, dA + 512);
            gload16(sB, dB);
            gload16(sB + 16 * ldb, dB + 512);
        }
        __builtin_amdgcn_sched_barrier(0);
        __builtin_amdgcn_s_barrier();
        asm volatile("s_waitcnt lgkmcnt(0)" ::: "memory");
        __builtin_amdgcn_sched_barrier(0);
        __builtin_amdgcn_s_setprio(1);
#pragma unroll
        for (int i = 0; i < 8; ++i)
#pragma unroll
            for (int j = 0; j < 4; ++j)
                acc[i][j] = __builtin_amdgcn_mfma_f32_16x16x32_bf16(
                    af[i], bf[j], acc[i][j], 0, 0, 0);
        __builtin_amdgcn_s_setprio(0);
        if (t + 3 < NT)      asm volatile("s_waitcnt vmcnt(8)" ::: "memory");
        else if (t + 2 < NT) asm volatile("s_waitcnt vmcnt(4)" ::: "memory");
        else if (t + 1 < NT) asm volatile("s_waitcnt vmcnt(0)" ::: "memory");
        __builtin_amdgcn_sched_barrier(0);
        __builtin_amdgcn_s_barrier();
    }

    const int mw = m0 + wr * 128;
    const int nw = n0 + wc * 64;
    const int rb = quad * 4;
#pragma unroll
    for (int i = 0; i < 8; ++i) {
#pragma unroll
        for (int j = 0; j < 4; ++j) {
            const int n = nw + j * 16 + r16;
#pragma unroll
            for (int r = 0; r < 4; ++r) {
                const int m = mw + i * 16 + rb + r;
                float v = acc[i][j][r];
                if (OUTM == 1)
                    ((float*)Cv)[(size_t)m * ldc + n] = v;
                else
                    ((u16*)Cv)[(size_t)m * ldc + n] = f2b(v);
            }
        }
    }
}

// =====================================================================
// 256x128-tile variant for GEMM6 (N=1024).  3-deep circular buffer,
// 2 blocks/CU, XCD swizzle.  Grid must be (8, 32).
// =====================================================================
template<int OUTM>
__global__ __launch_bounds__(512, 4) void gemm256n128(
    const u16* __restrict__ A, const u16* __restrict__ Bm,
    void* __restrict__ Cv,
    int K, int lda, int ldb, int ldc)
{
    __shared__ alignas(16) u16 ldsA[3][256 * 32];   // 48 KiB
    __shared__ alignas(16) u16 ldsB[3][128 * 32];   // 24 KiB

    int bx, by;
    xcd_swizzle<8, 32>(bx, by);

    const int lane = threadIdx.x & 63;
    const int wave = threadIdx.x >> 6;
    const int wr = wave >> 1;
    const int wc = wave & 1;
    const int m0 = by * 256;
    const int n0 = bx * 128;

    const int lrow = lane >> 2;
    const int skc  = (((lane & 3) + (lane >> 3)) & 3) * 8;
    const u16* pA = A  + (size_t)(m0 + wave * 32 + lrow) * lda + skc;
    const u16* pB = Bm + (size_t)(n0 + wave * 16 + lrow) * ldb + skc;
    const int ldstA = wave * 1024;
    const int ldstB = wave * 512;

    const int r16 = lane & 15;
    const int quad = lane >> 4;
    const int slot = (quad + 4 - ((r16 >> 1) & 3)) & 3;
    const int aoff = (wr * 64 + r16) * 32 + slot * 8;
    const int boff = (wc * 64 + r16) * 32 + slot * 8;

    const int NT = K >> 5;

    floatx4 acc[4][4] = {};

#pragma unroll
    for (int t = 0; t < 2; ++t) {
        gload16(pA + t * 32,            &ldsA[t][ldstA]);
        gload16(pA + t * 32 + 16 * lda, &ldsA[t][ldstA + 512]);
        gload16(pB + t * 32,            &ldsB[t][ldstB]);
    }
    asm volatile("s_waitcnt vmcnt(3)" ::: "memory");
    __builtin_amdgcn_sched_barrier(0);
    __builtin_amdgcn_s_barrier();

    int bc = 0, bs = 2;
    for (int t = 0; t < NT; ++t) {
        const u16* la = &ldsA[bc][aoff];
        const u16* lb = &ldsB[bc][boff];
        short8 af[4], bf[4];
#pragma unroll
        for (int i = 0; i < 4; ++i) af[i] = *(const short8*)(la + i * 512);
#pragma unroll
        for (int j = 0; j < 4; ++j) bf[j] = *(const short8*)(lb + j * 512);
        if (t + 2 < NT) {
            const u16* sa = pA + (t + 2) * 32;
            u16* da = &ldsA[bs][ldstA];
            gload16(sa, da);
            gload16(sa + 16 * lda, da + 512);
            gload16(pB + (t + 2) * 32, &ldsB[bs][ldstB]);
        }
        __builtin_amdgcn_sched_barrier(0);
        __builtin_amdgcn_s_barrier();
        asm volatile("s_waitcnt lgkmcnt(0)" ::: "memory");
        __builtin_amdgcn_sched_barrier(0);
        __builtin_amdgcn_s_setprio(1);
#pragma unroll
        for (int i = 0; i < 4; ++i)
#pragma unroll
            for (int j = 0; j < 4; ++j)
                acc[i][j] = __builtin_amdgcn_mfma_f32_16x16x32_bf16(
                    af[i], bf[j], acc[i][j], 0, 0, 0);
        __builtin_amdgcn_s_setprio(0);
        if (t + 2 < NT)      asm volatile("s_waitcnt vmcnt(3)" ::: "memory");
        else if (t + 1 < NT) asm volatile("s_waitcnt vmcnt(0)" ::: "memory");
        __builtin_amdgcn_sched_barrier(0);
        __builtin_amdgcn_s_barrier();
        bc = (bc == 2) ? 0 : bc + 1;
        bs = (bs == 2) ? 0 : bs + 1;
    }

    const int mw = m0 + wr * 64;
    const int nw = n0 + wc * 64;
    const int rb = quad * 4;
#pragma unroll
    for (int i = 0; i < 4; ++i) {
#pragma unroll
        for (int j = 0; j < 4; ++j) {
            const int n = nw + j * 16 + r16;
#pragma unroll
            for (int r = 0; r < 4; ++r) {
                const int m = mw + i * 16 + rb + r;
                float v = acc[i][j][r];
                if (OUTM == 1)
                    ((float*)Cv)[(size_t)m * ldc + n] = v;
                else
                    ((u16*)Cv)[(size_t)m * ldc + n] = f2b(v);
            }
        }
    }
}

// =====================================================================
// m97-structure GEMM.
// OUTM: 2 = fast-softplus(acc + bias[n]) bf16 (GEMM4),
//       4 = split-K partial: fp32 store, k-slice = blockIdx.z (GEMM3,
//           n >= 96 stores skipped: zero-pad cols, nothing reads them).
// =====================================================================
template<int OUTM>
__global__ __launch_bounds__(256) void gemm_bt(
    const u16* __restrict__ A, const u16* __restrict__ Bm,
    void* __restrict__ Cv, const float* __restrict__ bias,
    int K, int lda, int ldb, int ldc)
{
    __shared__ alignas(16) u16 ldsA[128 * 32];
    __shared__ alignas(16) u16 ldsB[128 * 32];

    const int lane = threadIdx.x & 63;
    const int wave = threadIdx.x >> 6;
    const int wr = wave >> 1, wc = wave & 1;
    const int m0 = blockIdx.y * 128;
    const int n0 = blockIdx.x * 128;
    const int koff = (OUTM == 4) ? blockIdx.z * K : 0;

    const int srow = wave * 32 + (lane >> 2);
    const int skc  = (((lane & 3) + (lane >> 3)) & 3) * 8;
    const u16* Ag = A + (size_t)(m0 + srow) * lda + skc + koff;
    const u16* Bg = Bm + (size_t)(n0 + srow) * ldb + skc + koff;
    u16* lA = &ldsA[wave * 1024];
    u16* lB = &ldsB[wave * 1024];

    const int r16 = lane & 15;
    const int quad = lane >> 4;
    const int slot = (quad + 4 - ((r16 >> 1) & 3)) & 3;
    const u16* arow = &ldsA[(wr * 64 + r16) * 32 + slot * 8];
    const u16* brow = &ldsB[(wc * 64 + r16) * 32 + slot * 8];

    floatx4 acc[4][4] = {};

    for (int k0 = 0; k0 < K; k0 += 32) {
        gload16(Ag + k0,                    lA);
        gload16(Ag + k0 + (size_t)16 * lda, lA + 512);
        gload16(Bg + k0,                    lB);
        gload16(Bg + k0 + (size_t)16 * ldb, lB + 512);
        __syncthreads();

        short8 af[4], bf[4];
#pragma unroll
        for (int i = 0; i < 4; i++) af[i] = *(const short8*)(arow + i * 16 * 32);
#pragma unroll
        for (int j = 0; j < 4; j++) bf[j] = *(const short8*)(brow + j * 16 * 32);
#pragma unroll
        for (int i = 0; i < 4; i++)
#pragma unroll
            for (int j = 0; j < 4; j++)
                acc[i][j] = __builtin_amdgcn_mfma_f32_16x16x32_bf16(
                    af[i], bf[j], acc[i][j], 0, 0, 0);
        __syncthreads();
    }

    const int mw = m0 + wr * 64;
    const int nw = n0 + wc * 64;
    const int rb = quad * 4;
#pragma unroll
    for (int i = 0; i < 4; i++) {
#pragma unroll
        for (int j = 0; j < 4; j++) {
            const int n = nw + j * 16 + r16;
            if (OUTM == 4 && n >= 96) continue;   // dead zero-pad cols
#pragma unroll
            for (int r = 0; r < 4; r++) {
                const int m = mw + i * 16 + rb + r;
                float v = acc[i][j][r];
                if (OUTM == 2)
                    v = softplus_fast(v + bias[n]);
                if (OUTM == 4)
                    ((float*)Cv)[((size_t)blockIdx.z * M + m) * ldc + n] = v;
                else if (OUTM == 1)
                    ((float*)Cv)[(size_t)m * ldc + n] = v;
                else
                    ((u16*)Cv)[(size_t)m * ldc + n] = f2b(v);
            }
        }
    }
}

// =====================================================================
// reduce 4 split-K fp32 partials -> compact 64-wide bf16 xdbl (dt_r)
// + fp32 bcf sideband (cols 64..95).  Done ONCE (R7 lesson: fusing this
// into GEMM4's blocks repeated it 16x -> VALU-bound).
// =====================================================================
__global__ __launch_bounds__(256) void redk_gemm3(
    const float* __restrict__ part, u16* __restrict__ xdbl,
    float* __restrict__ bcf)
{
    const int t = blockIdx.x * 256 + threadIdx.x;   // over M*24
    const int c4 = t % 24;
    const int m = t / 24;
    const int n4 = c4 * 4;                           // 0..92
    const size_t stride = (size_t)M * NPAD;
    const float* p = part + (size_t)m * NPAD + n4;
    floatx4 acc = *(const floatx4*)(p)
                + *(const floatx4*)(p + stride)
                + *(const floatx4*)(p + 2 * stride)
                + *(const floatx4*)(p + 3 * stride);
    if (n4 < 64) {
        short4v ob;
#pragma unroll
        for (int j = 0; j < 4; j++) ob[j] = (short)f2b(acc[j]);
        *(short4v*)(xdbl + (size_t)m * 64 + n4) = ob;
    } else {
        *(floatx4*)(bcf + (size_t)m * 32 + (n4 - 64)) = acc;
    }
}

// =====================================================================
// merged operand prep: x cvt | W_in cvt | W_x pad | W_dt cvt | W_out cvt
// =====================================================================
__global__ __launch_bounds__(256) void prep_all(
    const float* __restrict__ x, const float* __restrict__ W_in,
    const float* __restrict__ W_x, const float* __restrict__ W_dt,
    const float* __restrict__ W_out,
    u16* __restrict__ xbf, u16* __restrict__ wibf, u16* __restrict__ wxp,
    u16* __restrict__ wdtb, u16* __restrict__ woutb)
{
    constexpr int N0 = M * DM;
    constexpr int N1 = 2 * DI * DM;
    constexpr int N2 = NPAD * DI;
    constexpr int N3 = DI * DTR;
    int idx = blockIdx.x * blockDim.x + threadIdx.x;
    if (idx < N0) {
        xbf[idx] = f2b(x[idx]);
        return;
    }
    idx -= N0;
    if (idx < N1) {
        wibf[idx] = f2b(W_in[idx]);
    } else if (idx < N1 + N2) {
        int i = idx - N1;
        int r = i >> 11, c = i & 2047;
        wxp[i] = (r < 96) ? f2b(W_x[r * 2048 + c]) : (u16)0;
    } else if (idx < N1 + N2 + N3) {
        int i = idx - N1 - N2;
        wdtb[i] = f2b(W_dt[i]);
    } else {
        int i = idx - N1 - N2 - N3;
        woutb[i] = f2b(W_out[i]);
    }
}

// =====================================================================
// Depthwise causal conv (K=4) + SiLU, vectorized.
// =====================================================================
__global__ __launch_bounds__(256) void conv_silu(
    const u16* __restrict__ xz, const float* __restrict__ conv_w,
    const float* __restrict__ conv_b, u16* __restrict__ xs)
{
    const int m = blockIdx.x;
    const int d0 = threadIdx.x * 8;
    const int l = m & (Ll - 1);

    float acc[8];
    {
        floatx4 cb0 = *(const floatx4*)(conv_b + d0);
        floatx4 cb1 = *(const floatx4*)(conv_b + d0 + 4);
#pragma unroll
        for (int j = 0; j < 4; j++) { acc[j] = cb0[j]; acc[4 + j] = cb1[j]; }
    }
    float w[8][KC];
#pragma unroll
    for (int jd = 0; jd < 8; jd++) {
        floatx4 wv = *(const floatx4*)(conv_w + (d0 + jd) * KC);
#pragma unroll
        for (int k = 0; k < KC; k++) w[jd][k] = wv[k];
    }
#pragma unroll
    for (int k = 0; k < KC; k++) {
        int li = l - (KC - 1) + k;
        if (li >= 0) {
            short8 xv = *(const short8*)(xz + (size_t)(m - (KC - 1) + k) * LDXZ + d0);
#pragma unroll
            for (int jd = 0; jd < 8; jd++)
                acc[jd] += b2f((u16)xv[jd]) * w[jd][k];
        }
    }
    short8 o;
#pragma unroll
    for (int jd = 0; jd < 8; jd++) {
        float s = acc[jd] / (1.f + __expf(-acc[jd]));
        o[jd] = (short)f2b(s);
    }
    *(short8*)(xs + (size_t)m * DI + d0) = o;
}

// =====================================================================
// Chunked selective scan, NCHUNK=32 (1024 blocks).  Inter-chunk state
// compressed via P_s = exp(a_s * sum(dt)); p1 stores h_end + sdt; p2
// reconstructs P and runs in-place.
// =====================================================================
__global__ __launch_bounds__(256) void scan_p1(
    const u16* __restrict__ xzdt, const u16* __restrict__ xs,
    const float* __restrict__ bcf, const float* __restrict__ A_log,
    float* __restrict__ scr_h, float* __restrict__ sdt_g)
{
    __shared__ alignas(16) float bcs[LC * 32];   // 8 KB

    const int d = blockIdx.x * 256 + threadIdx.x;
    const int b = blockIdx.y;
    const int c = blockIdx.z;
    const int m0 = b * Ll + c * LC;

    {
        const float* bc_g = bcf + (size_t)m0 * 32;
#pragma unroll
        for (int j = 0; j < 2; j++) {
            int idx = j * 1024 + threadIdx.x * 4;
            *(floatx4*)(bcs + idx) = *(const floatx4*)(bc_g + idx);
        }
    }

    const float ad0 = -__expf(A_log[0]);
    float adl[DS];
    bool fast = true;
#pragma unroll
    for (int s = 0; s < DS; s++) {
        float av = -__expf(A_log[s]);
        adl[s] = av;
        float kr = (float)(s + 1);
        if (fabsf(av / ad0 - kr) > 1e-4f * kr) fast = false;
    }

    const u16* dt_p = xzdt + (size_t)m0 * LDXZ + d;
    const u16* xs_p = xs + (size_t)m0 * DI + d;

    float h[DS] = {};
    float sdt = 0.f;

    __syncthreads();

    u16 dt_c = dt_p[0],     xs_c = xs_p[0];
    u16 dt_1 = dt_p[LDXZ],  xs_1 = xs_p[DI];

    if (fast) {
        for (int l = 0; l < LC; l++) {
            u16 dt_2 = dt_p[2 * LDXZ];
            u16 xs_2 = xs_p[2 * DI];
            const float* bl = bcs + l * 32;
            floatx4 B0 = *(const floatx4*)(bl);
            floatx4 B1 = *(const floatx4*)(bl + 4);
            floatx4 B2 = *(const floatx4*)(bl + 8);
            floatx4 B3 = *(const floatx4*)(bl + 12);

            float dtv = b2f(dt_c);
            float xv  = b2f(xs_c);
            float bx = dtv * xv;
            sdt += dtv;
            float aa[DS];
            pow_tree(__expf(dtv * ad0), aa);
#pragma unroll
            for (int s = 0; s < DS; s++) {
                float Bv = (s < 4) ? B0[s] : (s < 8) ? B1[s - 4]
                         : (s < 12) ? B2[s - 8] : B3[s - 12];
                h[s] = aa[s] * h[s] + bx * Bv;
            }
            dt_c = dt_1; dt_1 = dt_2; xs_c = xs_1; xs_1 = xs_2;
            dt_p += LDXZ; xs_p += DI;
        }
    } else {
        for (int l = 0; l < LC; l++) {
            u16 dt_2 = dt_p[2 * LDXZ];
            u16 xs_2 = xs_p[2 * DI];
            const float* bl = bcs + l * 32;
            floatx4 B0 = *(const floatx4*)(bl);
            floatx4 B1 = *(const floatx4*)(bl + 4);
            floatx4 B2 = *(const floatx4*)(bl + 8);
            floatx4 B3 = *(const floatx4*)(bl + 12);

            float dtv = b2f(dt_c);
            float xv  = b2f(xs_c);
            float bx = dtv * xv;
            sdt += dtv;
#pragma unroll
            for (int s = 0; s < DS; s++) {
                float Bv = (s < 4) ? B0[s] : (s < 8) ? B1[s - 4]
                         : (s < 12) ? B2[s - 8] : B3[s - 12];
                float a = __expf(dtv * adl[s]);
                h[s] = a * h[s] + bx * Bv;
            }
            dt_c = dt_1; dt_1 = dt_2; xs_c = xs_1; xs_1 = xs_2;
            dt_p += LDXZ; xs_p += DI;
        }
    }

    const size_t base = ((size_t)(b * NCHUNK + c) * DI + d) * DS;
#pragma unroll
    for (int s = 0; s < DS; s += 4) {
        floatx4 hv = {h[s], h[s+1], h[s+2], h[s+3]};
        *(floatx4*)(scr_h + base + s) = hv;
    }
    sdt_g[(size_t)(b * NCHUNK + c) * DI + d] = sdt;
}

// in-place chunk-prefix: scr_h holds h_end on entry, h_in on exit
__global__ __launch_bounds__(256) void scan_p2(
    float* __restrict__ scr_h, const float* __restrict__ sdt_g,
    const float* __restrict__ A_log)
{
    const int t = blockIdx.x * 256 + threadIdx.x;   // (b, d, s)
    const int s = t & 15;
    const int d = (t >> 4) & (DI - 1);
    const int b = t >> 15;
    const float adl = -__expf(A_log[s]);

    float hin = 0.f;
    for (int c0 = 0; c0 < NCHUNK; c0 += 8) {
        float he[8], P[8];
#pragma unroll
        for (int j = 0; j < 8; j++) {
            const size_t base = ((size_t)(b * NCHUNK + c0 + j) * DI + d) * DS + s;
            he[j] = scr_h[base];
            P[j] = adl * sdt_g[(size_t)(b * NCHUNK + c0 + j) * DI + d];
        }
#pragma unroll
        for (int j = 0; j < 8; j++) P[j] = __expf(P[j]);
#pragma unroll
        for (int j = 0; j < 8; j++) {
            const size_t base = ((size_t)(b * NCHUNK + c0 + j) * DI + d) * DS + s;
            scr_h[base] = hin;
            hin = P[j] * hin + he[j];
        }
    }
}

__global__ __launch_bounds__(256) void scan_p3(
    const u16* __restrict__ xz, const u16* xs, const float* __restrict__ bcf,
    const float* __restrict__ scr_hin, const float* __restrict__ A_log,
    const float* __restrict__ Dvec, u16* yg)
{
    __shared__ alignas(16) float bcs[LC * 32];   // 8 KB

    const int d = blockIdx.x * 256 + threadIdx.x;
    const int b = blockIdx.y;
    const int c = blockIdx.z;
    const int m0 = b * Ll + c * LC;

    {
        const float* bc_g = bcf + (size_t)m0 * 32;
#pragma unroll
        for (int j = 0; j < 2; j++) {
            int idx = j * 1024 + threadIdx.x * 4;
            *(floatx4*)(bcs + idx) = *(const floatx4*)(bc_g + idx);
        }
    }

    const float ad0 = -__expf(A_log[0]);
    float adl[DS];
    bool fast = true;
#pragma unroll
    for (int s = 0; s < DS; s++) {
        float av = -__expf(A_log[s]);
        adl[s] = av;
        float kr = (float)(s + 1);
        if (fabsf(av / ad0 - kr) > 1e-4f * kr) fast = false;
    }
    const float Dd = Dvec[d];

    const u16* dt_p = xz + (size_t)m0 * LDXZ + d;
    const u16* z_p  = xz + (size_t)m0 * LDXZ + 2048 + d;
    const u16* xs_p = xs + (size_t)m0 * DI + d;
    u16* yg_p = yg + (size_t)m0 * DI + d;

    float h[DS];
    const size_t base = ((size_t)(b * NCHUNK + c) * DI + d) * DS;
#pragma unroll
    for (int s = 0; s < DS; s += 4) {
        floatx4 hv = *(const floatx4*)(scr_hin + base + s);
        h[s] = hv[0]; h[s+1] = hv[1]; h[s+2] = hv[2]; h[s+3] = hv[3];
    }

    __syncthreads();

    u16 dt_c = dt_p[0],    dt_1 = dt_p[LDXZ];
    u16 xs_c = xs_p[0],    xs_1 = xs_p[DI];
    u16 z_c  = z_p[0],     z_1  = z_p[LDXZ];

    for (int l = 0; l < LC; l++) {
        u16 dt_2 = dt_p[2 * LDXZ];
        u16 xs_2 = xs_p[2 * DI];
        u16 z_2  = z_p[2 * LDXZ];
        const float* bl = bcs + l * 32;
        floatx4 Bq[4], Cq[4];
#pragma unroll
        for (int q = 0; q < 4; q++) {
            Bq[q] = *(const floatx4*)(bl + q * 4);
            Cq[q] = *(const floatx4*)(bl + 16 + q * 4);
        }

        float dtv = b2f(dt_c);
        float xv  = b2f(xs_c);
        float bx = dtv * xv;
        float aa[DS];
        if (fast) {
            pow_tree(__expf(dtv * ad0), aa);
        } else {
#pragma unroll
            for (int s = 0; s < DS; s++) aa[s] = __expf(dtv * adl[s]);
        }
        float y0 = 0.f, y1 = 0.f, y2 = 0.f, y3 = 0.f;
#pragma unroll
        for (int q = 0; q < 4; q++) {
#pragma unroll
            for (int j = 0; j < 4; j++) {
                int s = q * 4 + j;
                h[s] = aa[s] * h[s] + bx * Bq[q][j];
            }
        }
#pragma unroll
        for (int j = 0; j < 4; j++) {
            y0 += h[j] * Cq[0][j];
            y1 += h[4 + j] * Cq[1][j];
            y2 += h[8 + j] * Cq[2][j];
            y3 += h[12 + j] * Cq[3][j];
        }
        float yt = ((y0 + y1) + (y2 + y3)) + Dd * xv;
        float zv = b2f(z_c);
        float g = zv / (1.f + __expf(-zv));
        yg_p[0] = f2b(yt * g);

        dt_c = dt_1; dt_1 = dt_2;
        xs_c = xs_1; xs_1 = xs_2;
        z_c  = z_1;  z_1  = z_2;
        dt_p += LDXZ; xs_p += DI; z_p += LDXZ; yg_p += DI;
    }
}

// =====================================================================
extern "C" void kernel_launch(void* const* d_in, const int* in_sizes, int n_in,
                              void* d_out, int out_size, void* d_ws, size_t ws_size,
                              hipStream_t stream)
{
    const float* x      = (const float*)d_in[0];
    const float* W_in   = (const float*)d_in[1];
    const float* conv_w = (const float*)d_in[2];
    const float* conv_b = (const float*)d_in[3];
    const float* A_log  = (const float*)d_in[4];
    const float* Dvec   = (const float*)d_in[5];
    const float* W_x    = (const float*)d_in[6];
    const float* W_dt   = (const float*)d_in[7];
    const float* b_dt   = (const float*)d_in[8];
    const float* W_out  = (const float*)d_in[9];

    // ---- workspace arena (bf16 u16 elements), ~133 MB total ----
    u16* ws = (u16*)d_ws;
    u16* xz    = ws;                 ws += (size_t)M * LDXZ;     // 67.1 MB
    u16* xs    = ws;                 ws += (size_t)M * DI;       // 33.55 MB (yg in-place)
    u16* xbf   = ws;                 ws += (size_t)M * DM;       // 16.78 MB
    u16* wibf  = ws;                 ws += (size_t)2 * DI * DM;  // 8.39 MB (reused as bcf+sdt)
    u16* wxp   = ws;                 ws += (size_t)NPAD * DI;    // 0.52 MB
    u16* wdtb  = ws;                 ws += (size_t)DI * DTR;     // 0.26 MB
    u16* woutb = ws;                 ws += (size_t)DM * DI;      // 4.19 MB
    u16* xdbl  = ws;                 ws += (size_t)M * NPAD;     // 2.10 MB (M*64 used)
    float* part  = (float*)xbf;      // split-K partials (xbf dead after GEMM1)
    float* scr_h = (float*)xbf;      // scan h scratch (part dead after redk)
    float* bcf   = (float*)wibf;     // 1.05 MB (wibf dead after GEMM1)
    float* sdt_g = bcf + (size_t)M * 32;   // 1.05 MB, inside wibf region

    // 0) merged operand prep
    {
        constexpr int NTOT = M * DM + 2 * DI * DM + NPAD * DI + DI * DTR + DM * DI;
        prep_all<<<NTOT / 256, 256, 0, stream>>>(
            x, W_in, W_x, W_dt, W_out, xbf, wibf, wxp, wdtb, woutb);
    }

    // 1) xz = x @ W_in^T   (8192 x 4096, K=1024)
    gemm256<0><<<dim3(LDXZ / 256, M / 256), 512, 0, stream>>>(
        xbf, wibf, xz, DM, DM, DM, LDXZ);

    // 2) conv + silu -> xs
    conv_silu<<<M, 256, 0, stream>>>(xz, conv_w, conv_b, xs);

    // 3) x_dbl partials = xs @ wxp^T, split-K x4 (cols 0..95), then reduce once
    gemm_bt<4><<<dim3(1, M / 128, 4), 256, 0, stream>>>(
        xs, wxp, part, nullptr, DI / 4, DI, DI, NPAD);
    redk_gemm3<<<(M * 24) / 256, 256, 0, stream>>>(part, xdbl, bcf);

    // 4) dt = fast-softplus(xdbl @ W_dt^T + b_dt) -> xr half of xz
    gemm_bt<2><<<dim3(DI / 128, M / 128), 256, 0, stream>>>(
        xdbl, wdtb, xz, b_dt, DTR, 64, DTR, LDXZ);

    // 5) chunked scan
    scan_p1<<<dim3(DI / 256, Bb, NCHUNK), 256, 0, stream>>>(
        xz, xs, bcf, A_log, scr_h, sdt_g);
    scan_p2<<<(Bb * DI * DS) / 256, 256, 0, stream>>>(scr_h, sdt_g, A_log);
    scan_p3<<<dim3(DI / 256, Bb, NCHUNK), 256, 0, stream>>>(
        xz, xs, bcf, scr_h, A_log, Dvec, xs);

    // 6) out = yg @ W_out^T   (8192 x 1024, K=2048)
    gemm256n128<1><<<dim3(DM / 128, M / 256), 512, 0, stream>>>(
        xs, woutb, d_out, DI, DI, DI, DM);
}

// Round 9
// 394.522 us; speedup vs baseline: 1.7121x; 1.0532x over previous
//
#include <hip/hip_runtime.h>
#include <math.h>

typedef unsigned short u16;
typedef unsigned int u32;

// ---- problem constants ----
constexpr int Bb = 4, Ll = 2048, DM = 1024, DI = 2048, DS = 16, DTR = 64, KC = 4;
constexpr int M = Bb * Ll;            // 8192 rows
constexpr int NPAD = 128;             // padded x_dbl width (64 + 2*16 = 96 -> 128)
constexpr int NCHUNK = 32;            // scan chunks
constexpr int LC = Ll / NCHUNK;       // 64 steps per chunk
constexpr int LDXZ = 4096;            // xz row stride (xr|z interleaved)

// ---- bf16 helpers on raw u16 ----
__device__ __forceinline__ float b2f(u16 u) {
    return __uint_as_float(((u32)u) << 16);
}
__device__ __forceinline__ u16 f2b(float f) {
    u32 x = __float_as_uint(f);
    u32 r = (x + 0x7fffu + ((x >> 16) & 1u)) >> 16;   // round-to-nearest-even
    return (u16)r;
}
// fast softplus: v_exp_f32 + v_log_f32 (~8 VALU ops) instead of the
// OCML log1pf libcall (R7/R8 finding: log1pf epilogue was ~50us of VALU).
__device__ __forceinline__ float softplus_fast(float v) {
    return (v > 20.f) ? v : __logf(1.f + __expf(v));
}

typedef __attribute__((ext_vector_type(8))) short short8;
typedef __attribute__((ext_vector_type(4))) short short4v;
typedef __attribute__((ext_vector_type(4))) float floatx4;

// async global->LDS, 16B per lane; LDS dest = wave-uniform base + lane*16
__device__ __forceinline__ void gload16(const u16* g, u16* l) {
    __builtin_amdgcn_global_load_lds(
        (const __attribute__((address_space(1))) void*)g,
        (__attribute__((address_space(3))) void*)l,
        16, 0, 0);
}

// a^(s+1) for s=0..15 from base a, tree form (15 muls, depth 4)
__device__ __forceinline__ void pow_tree(float a, float* aa) {
    float a2 = a * a, a4 = a2 * a2, a8 = a4 * a4;
    aa[0] = a;        aa[1] = a2;       aa[2] = a * a2;   aa[3] = a4;
    aa[4] = a * a4;   aa[5] = a2 * a4;  aa[6] = aa[2] * a4; aa[7] = a8;
    aa[8] = a * a8;   aa[9] = a2 * a8;  aa[10] = aa[2] * a8; aa[11] = a4 * a8;
    aa[12] = aa[4] * a8; aa[13] = aa[5] * a8; aa[14] = aa[6] * a8; aa[15] = a8 * a8;
}

// XCD-chunked bijective blockIdx swizzle (T1, m204-style).
template<int GX, int GY>
__device__ __forceinline__ void xcd_swizzle(int& bx, int& by) {
    const int bid = blockIdx.y * GX + blockIdx.x;
    const int xcd = bid & 7;
    const int i = bid >> 3;
    const int c_local = i >> 5;
    const int within = i & 31;
    const int lx = within & 7, ly = within >> 3;
    const int chunk = xcd + c_local * 8;
    constexpr int CXN = GX / 8;
    const int cx = chunk % CXN;
    const int cy = chunk / CXN;
    bx = cx * 8 + lx;
    by = cy * 4 + ly;
}

// =====================================================================
// Big-tile GEMM: 256x256 tile, 8 waves (2M x 4N), BK=32, 4-deep
// circular LDS buffer, one phase per K-tile, counted vmcnt(8),
// setprio, XCD swizzle.  846 TF @ K=1024 (R4) = catalog level (m248).
// OUTM: 0 = bf16 store, 1 = fp32 store.  Grid must be (16, 32).
// =====================================================================
template<int OUTM>
__global__ __launch_bounds__(512, 2) void gemm256(
    const u16* __restrict__ A, const u16* __restrict__ Bm,
    void* __restrict__ Cv,
    int K, int lda, int ldb, int ldc)
{
    __shared__ alignas(16) u16 ldsA[4][256 * 32];   // 64 KiB
    __shared__ alignas(16) u16 ldsB[4][256 * 32];   // 64 KiB

    int bx, by;
    xcd_swizzle<16, 32>(bx, by);

    const int lane = threadIdx.x & 63;
    const int wave = threadIdx.x >> 6;
    const int wr = wave >> 2;
    const int wc = wave & 3;
    const int m0 = by * 256;
    const int n0 = bx * 256;

    const int lrow = lane >> 2;
    const int skc  = (((lane & 3) + (lane >> 3)) & 3) * 8;
    const u16* pA = A  + (size_t)(m0 + wave * 32 + lrow) * lda + skc;
    const u16* pB = Bm + (size_t)(n0 + wave * 32 + lrow) * ldb + skc;
    const int ldst = wave * 1024;

    const int r16 = lane & 15;
    const int quad = lane >> 4;
    const int slot = (quad + 4 - ((r16 >> 1) & 3)) & 3;
    const int aoff = (wr * 128 + r16) * 32 + slot * 8;
    const int boff = (wc * 64  + r16) * 32 + slot * 8;

    const int NT = K >> 5;

    floatx4 acc[8][4] = {};

#pragma unroll
    for (int t = 0; t < 3; ++t) {
        gload16(pA + t * 32,            &ldsA[t][ldst]);
        gload16(pA + t * 32 + 16 * lda, &ldsA[t][ldst + 512]);
        gload16(pB + t * 32,            &ldsB[t][ldst]);
        gload16(pB + t * 32 + 16 * ldb, &ldsB[t][ldst + 512]);
    }
    asm volatile("s_waitcnt vmcnt(8)" ::: "memory");
    __builtin_amdgcn_sched_barrier(0);
    __builtin_amdgcn_s_barrier();

    for (int t = 0; t < NT; ++t) {
        const u16* la = &ldsA[t & 3][aoff];
        const u16* lb = &ldsB[t & 3][boff];
        short8 af[8], bf[4];
#pragma unroll
        for (int i = 0; i < 8; ++i) af[i] = *(const short8*)(la + i * 512);
#pragma unroll
        for (int j = 0; j < 4; ++j) bf[j] = *(const short8*)(lb + j * 512);
        if (t + 3 < NT) {
            const u16* sA = pA + (t + 3) * 32;
            const u16* sB = pB + (t + 3) * 32;
            u16* dA = &ldsA[(t + 3) & 3][ldst];
            u16* dB = &ldsB[(t + 3) & 3][ldst];
            gload16(sA, dA);
            gload16(sA + 16 * lda, dA + 512);
            gload16(sB, dB);
            gload16(sB + 16 * ldb, dB + 512);
        }
        __builtin_amdgcn_sched_barrier(0);
        __builtin_amdgcn_s_barrier();
        asm volatile("s_waitcnt lgkmcnt(0)" ::: "memory");
        __builtin_amdgcn_sched_barrier(0);
        __builtin_amdgcn_s_setprio(1);
#pragma unroll
        for (int i = 0; i < 8; ++i)
#pragma unroll
            for (int j = 0; j < 4; ++j)
                acc[i][j] = __builtin_amdgcn_mfma_f32_16x16x32_bf16(
                    af[i], bf[j], acc[i][j], 0, 0, 0);
        __builtin_amdgcn_s_setprio(0);
        if (t + 3 < NT)      asm volatile("s_waitcnt vmcnt(8)" ::: "memory");
        else if (t + 2 < NT) asm volatile("s_waitcnt vmcnt(4)" ::: "memory");
        else if (t + 1 < NT) asm volatile("s_waitcnt vmcnt(0)" ::: "memory");
        __builtin_amdgcn_sched_barrier(0);
        __builtin_amdgcn_s_barrier();
    }

    const int mw = m0 + wr * 128;
    const int nw = n0 + wc * 64;
    const int rb = quad * 4;
#pragma unroll
    for (int i = 0; i < 8; ++i) {
#pragma unroll
        for (int j = 0; j < 4; ++j) {
            const int n = nw + j * 16 + r16;
#pragma unroll
            for (int r = 0; r < 4; ++r) {
                const int m = mw + i * 16 + rb + r;
                float v = acc[i][j][r];
                if (OUTM == 1)
                    ((float*)Cv)[(size_t)m * ldc + n] = v;
                else
                    ((u16*)Cv)[(size_t)m * ldc + n] = f2b(v);
            }
        }
    }
}

// =====================================================================
// 256x128-tile variant for GEMM6 (N=1024).  R9: 6-deep circular buffer
// (144 KiB LDS), TWO K-tiles per phase -> 32 MFMA + 16 ds_read + 6
// gloads per barrier-pair (matches gemm256's proven MFMA:barrier ratio;
// previous 16-MFMA/phase version wasted barrier bandwidth at the
// grid-256 = 1 block/CU occupancy).  Counted vmcnt(6) = 2 tiles in
// flight.  Requires NT even, NT >= 6.  Grid must be (8, 32).
// =====================================================================
template<int OUTM>
__global__ __launch_bounds__(512, 2) void gemm256n128(
    const u16* __restrict__ A, const u16* __restrict__ Bm,
    void* __restrict__ Cv,
    int K, int lda, int ldb, int ldc)
{
    __shared__ alignas(16) u16 ldsA[6][256 * 32];   // 96 KiB
    __shared__ alignas(16) u16 ldsB[6][128 * 32];   // 48 KiB

    int bx, by;
    xcd_swizzle<8, 32>(bx, by);

    const int lane = threadIdx.x & 63;
    const int wave = threadIdx.x >> 6;
    const int wr = wave >> 1;              // 0..3  (M quarter)
    const int wc = wave & 1;               // 0..1  (N half)
    const int m0 = by * 256;
    const int n0 = bx * 128;

    // A: wave stages 32 rows (2 gloads); B: wave stages 16 rows (1 gload).
    const int lrow = lane >> 2;
    const int skc  = (((lane & 3) + (lane >> 3)) & 3) * 8;
    const u16* pA = A  + (size_t)(m0 + wave * 32 + lrow) * lda + skc;
    const u16* pB = Bm + (size_t)(n0 + wave * 16 + lrow) * ldb + skc;
    const int ldstA = wave * 1024;
    const int ldstB = wave * 512;

    const int r16 = lane & 15;
    const int quad = lane >> 4;
    const int slot = (quad + 4 - ((r16 >> 1) & 3)) & 3;
    const int aoff = (wr * 64 + r16) * 32 + slot * 8;
    const int boff = (wc * 64 + r16) * 32 + slot * 8;

    const int NT = K >> 5;                 // K-tiles of 32 (even)
    const int NP = NT >> 1;                // phases

    floatx4 acc[4][4] = {};

    // ---- prologue: stage tiles 0..3 into bufs 0..3 (12 gloads) ----
#pragma unroll
    for (int t = 0; t < 4; ++t) {
        gload16(pA + t * 32,            &ldsA[t][ldstA]);
        gload16(pA + t * 32 + 16 * lda, &ldsA[t][ldstA + 512]);
        gload16(pB + t * 32,            &ldsB[t][ldstB]);
    }
    asm volatile("s_waitcnt vmcnt(6)" ::: "memory");   // tiles 0,1 landed
    __builtin_amdgcn_sched_barrier(0);
    __builtin_amdgcn_s_barrier();

    int b0 = 0, b1 = 1, s0 = 4, s1 = 5;    // consume bufs / stage bufs (mod 6)
    for (int p = 0; p < NP; ++p) {
        const int t0 = 2 * p;
        const u16* la0 = &ldsA[b0][aoff];
        const u16* lb0 = &ldsB[b0][boff];
        const u16* la1 = &ldsA[b1][aoff];
        const u16* lb1 = &ldsB[b1][boff];
        short8 af0[4], bf0[4], af1[4], bf1[4];
#pragma unroll
        for (int i = 0; i < 4; ++i) {
            af0[i] = *(const short8*)(la0 + i * 512);
            af1[i] = *(const short8*)(la1 + i * 512);
            bf0[i] = *(const short8*)(lb0 + i * 512);
            bf1[i] = *(const short8*)(lb1 + i * 512);
        }
        if (t0 + 4 < NT) {                 // stage tiles t0+4, t0+5
            const u16* sa0 = pA + (t0 + 4) * 32;
            const u16* sa1 = pA + (t0 + 5) * 32;
            u16* da0 = &ldsA[s0][ldstA];
            u16* da1 = &ldsA[s1][ldstA];
            gload16(sa0, da0);
            gload16(sa0 + 16 * lda, da0 + 512);
            gload16(pB + (t0 + 4) * 32, &ldsB[s0][ldstB]);
            gload16(sa1, da1);
            gload16(sa1 + 16 * lda, da1 + 512);
            gload16(pB + (t0 + 5) * 32, &ldsB[s1][ldstB]);
        }
        __builtin_amdgcn_sched_barrier(0);
        __builtin_amdgcn_s_barrier();
        asm volatile("s_waitcnt lgkmcnt(0)" ::: "memory");
        __builtin_amdgcn_sched_barrier(0);
        __builtin_amdgcn_s_setprio(1);
#pragma unroll
        for (int i = 0; i < 4; ++i)
#pragma unroll
            for (int j = 0; j < 4; ++j)
                acc[i][j] = __builtin_amdgcn_mfma_f32_16x16x32_bf16(
                    af0[i], bf0[j], acc[i][j], 0, 0, 0);
#pragma unroll
        for (int i = 0; i < 4; ++i)
#pragma unroll
            for (int j = 0; j < 4; ++j)
                acc[i][j] = __builtin_amdgcn_mfma_f32_16x16x32_bf16(
                    af1[i], bf1[j], acc[i][j], 0, 0, 0);
        __builtin_amdgcn_s_setprio(0);
        // counted vmcnt: tiles t0+2,t0+3 must be landed; t0+4,t0+5 stay in flight
        if (t0 + 4 < NT)      asm volatile("s_waitcnt vmcnt(6)" ::: "memory");
        else if (t0 + 2 < NT) asm volatile("s_waitcnt vmcnt(0)" ::: "memory");
        __builtin_amdgcn_sched_barrier(0);
        __builtin_amdgcn_s_barrier();
        b0 += 2; if (b0 >= 6) b0 -= 6;
        b1 += 2; if (b1 >= 6) b1 -= 6;
        s0 += 2; if (s0 >= 6) s0 -= 6;
        s1 += 2; if (s1 >= 6) s1 -= 6;
    }

    const int mw = m0 + wr * 64;
    const int nw = n0 + wc * 64;
    const int rb = quad * 4;
#pragma unroll
    for (int i = 0; i < 4; ++i) {
#pragma unroll
        for (int j = 0; j < 4; ++j) {
            const int n = nw + j * 16 + r16;
#pragma unroll
            for (int r = 0; r < 4; ++r) {
                const int m = mw + i * 16 + rb + r;
                float v = acc[i][j][r];
                if (OUTM == 1)
                    ((float*)Cv)[(size_t)m * ldc + n] = v;
                else
                    ((u16*)Cv)[(size_t)m * ldc + n] = f2b(v);
            }
        }
    }
}

// =====================================================================
// m97-structure GEMM.
// OUTM: 2 = fast-softplus(acc + bias[n]) bf16 (GEMM4),
//       4 = split-K partial: fp32 store, k-slice = blockIdx.z (GEMM3,
//           n >= 96 stores skipped: zero-pad cols, nothing reads them).
// =====================================================================
template<int OUTM>
__global__ __launch_bounds__(256) void gemm_bt(
    const u16* __restrict__ A, const u16* __restrict__ Bm,
    void* __restrict__ Cv, const float* __restrict__ bias,
    int K, int lda, int ldb, int ldc)
{
    __shared__ alignas(16) u16 ldsA[128 * 32];
    __shared__ alignas(16) u16 ldsB[128 * 32];

    const int lane = threadIdx.x & 63;
    const int wave = threadIdx.x >> 6;
    const int wr = wave >> 1, wc = wave & 1;
    const int m0 = blockIdx.y * 128;
    const int n0 = blockIdx.x * 128;
    const int koff = (OUTM == 4) ? blockIdx.z * K : 0;

    const int srow = wave * 32 + (lane >> 2);
    const int skc  = (((lane & 3) + (lane >> 3)) & 3) * 8;
    const u16* Ag = A + (size_t)(m0 + srow) * lda + skc + koff;
    const u16* Bg = Bm + (size_t)(n0 + srow) * ldb + skc + koff;
    u16* lA = &ldsA[wave * 1024];
    u16* lB = &ldsB[wave * 1024];

    const int r16 = lane & 15;
    const int quad = lane >> 4;
    const int slot = (quad + 4 - ((r16 >> 1) & 3)) & 3;
    const u16* arow = &ldsA[(wr * 64 + r16) * 32 + slot * 8];
    const u16* brow = &ldsB[(wc * 64 + r16) * 32 + slot * 8];

    floatx4 acc[4][4] = {};

    for (int k0 = 0; k0 < K; k0 += 32) {
        gload16(Ag + k0,                    lA);
        gload16(Ag + k0 + (size_t)16 * lda, lA + 512);
        gload16(Bg + k0,                    lB);
        gload16(Bg + k0 + (size_t)16 * ldb, lB + 512);
        __syncthreads();

        short8 af[4], bf[4];
#pragma unroll
        for (int i = 0; i < 4; i++) af[i] = *(const short8*)(arow + i * 16 * 32);
#pragma unroll
        for (int j = 0; j < 4; j++) bf[j] = *(const short8*)(brow + j * 16 * 32);
#pragma unroll
        for (int i = 0; i < 4; i++)
#pragma unroll
            for (int j = 0; j < 4; j++)
                acc[i][j] = __builtin_amdgcn_mfma_f32_16x16x32_bf16(
                    af[i], bf[j], acc[i][j], 0, 0, 0);
        __syncthreads();
    }

    const int mw = m0 + wr * 64;
    const int nw = n0 + wc * 64;
    const int rb = quad * 4;
#pragma unroll
    for (int i = 0; i < 4; i++) {
#pragma unroll
        for (int j = 0; j < 4; j++) {
            const int n = nw + j * 16 + r16;
            if (OUTM == 4 && n >= 96) continue;   // dead zero-pad cols
#pragma unroll
            for (int r = 0; r < 4; r++) {
                const int m = mw + i * 16 + rb + r;
                float v = acc[i][j][r];
                if (OUTM == 2)
                    v = softplus_fast(v + bias[n]);
                if (OUTM == 4)
                    ((float*)Cv)[((size_t)blockIdx.z * M + m) * ldc + n] = v;
                else if (OUTM == 1)
                    ((float*)Cv)[(size_t)m * ldc + n] = v;
                else
                    ((u16*)Cv)[(size_t)m * ldc + n] = f2b(v);
            }
        }
    }
}

// =====================================================================
// reduce 4 split-K fp32 partials -> compact 64-wide bf16 xdbl (dt_r)
// + fp32 bcf sideband (cols 64..95).  Done ONCE (R7 lesson).
// =====================================================================
__global__ __launch_bounds__(256) void redk_gemm3(
    const float* __restrict__ part, u16* __restrict__ xdbl,
    float* __restrict__ bcf)
{
    const int t = blockIdx.x * 256 + threadIdx.x;   // over M*24
    const int c4 = t % 24;
    const int m = t / 24;
    const int n4 = c4 * 4;                           // 0..92
    const size_t stride = (size_t)M * NPAD;
    const float* p = part + (size_t)m * NPAD + n4;
    floatx4 acc = *(const floatx4*)(p)
                + *(const floatx4*)(p + stride)
                + *(const floatx4*)(p + 2 * stride)
                + *(const floatx4*)(p + 3 * stride);
    if (n4 < 64) {
        short4v ob;
#pragma unroll
        for (int j = 0; j < 4; j++) ob[j] = (short)f2b(acc[j]);
        *(short4v*)(xdbl + (size_t)m * 64 + n4) = ob;
    } else {
        *(floatx4*)(bcf + (size_t)m * 32 + (n4 - 64)) = acc;
    }
}

// =====================================================================
// merged operand prep: x cvt | W_in cvt | W_x pad | W_dt cvt | W_out cvt
// =====================================================================
__global__ __launch_bounds__(256) void prep_all(
    const float* __restrict__ x, const float* __restrict__ W_in,
    const float* __restrict__ W_x, const float* __restrict__ W_dt,
    const float* __restrict__ W_out,
    u16* __restrict__ xbf, u16* __restrict__ wibf, u16* __restrict__ wxp,
    u16* __restrict__ wdtb, u16* __restrict__ woutb)
{
    constexpr int N0 = M * DM;
    constexpr int N1 = 2 * DI * DM;
    constexpr int N2 = NPAD * DI;
    constexpr int N3 = DI * DTR;
    int idx = blockIdx.x * blockDim.x + threadIdx.x;
    if (idx < N0) {
        xbf[idx] = f2b(x[idx]);
        return;
    }
    idx -= N0;
    if (idx < N1) {
        wibf[idx] = f2b(W_in[idx]);
    } else if (idx < N1 + N2) {
        int i = idx - N1;
        int r = i >> 11, c = i & 2047;
        wxp[i] = (r < 96) ? f2b(W_x[r * 2048 + c]) : (u16)0;
    } else if (idx < N1 + N2 + N3) {
        int i = idx - N1 - N2;
        wdtb[i] = f2b(W_dt[i]);
    } else {
        int i = idx - N1 - N2 - N3;
        woutb[i] = f2b(W_out[i]);
    }
}

// =====================================================================
// Depthwise causal conv (K=4) + SiLU.  R9: 8 rows per block with an
// 11-row register window -> 11 row-loads per 8 outputs instead of 32
// (the old per-row kernel re-fetched each xz row 4x).  8 | 2048 so a
// block never spans a batch boundary; rows with batch-local l < 0 are
// zeroed (causal padding).  Grid M/8 = 1024.
// =====================================================================
__global__ __launch_bounds__(256) void conv_silu8(
    const u16* __restrict__ xz, const float* __restrict__ conv_w,
    const float* __restrict__ conv_b, u16* __restrict__ xs)
{
    const int m0 = blockIdx.x * 8;
    const int d0 = threadIdx.x * 8;
    const int l0 = m0 & (Ll - 1);

    short8 xv[11];
#pragma unroll
    for (int j = 0; j < 11; j++) {
        if (l0 + j >= 3) {                 // row m0-3+j valid within batch
            xv[j] = *(const short8*)(xz + (size_t)(m0 - 3 + j) * LDXZ + d0);
        } else {
#pragma unroll
            for (int e = 0; e < 8; e++) xv[j][e] = 0;
        }
    }

    float w[8][KC];
#pragma unroll
    for (int jd = 0; jd < 8; jd++) {
        floatx4 wv = *(const floatx4*)(conv_w + (d0 + jd) * KC);
#pragma unroll
        for (int k = 0; k < KC; k++) w[jd][k] = wv[k];
    }
    float cb[8];
    {
        floatx4 cb0 = *(const floatx4*)(conv_b + d0);
        floatx4 cb1 = *(const floatx4*)(conv_b + d0 + 4);
#pragma unroll
        for (int j = 0; j < 4; j++) { cb[j] = cb0[j]; cb[4 + j] = cb1[j]; }
    }

#pragma unroll
    for (int j = 0; j < 8; j++) {          // output row m0+j, taps xv[j..j+3]
        float acc[8];
#pragma unroll
        for (int jd = 0; jd < 8; jd++) acc[jd] = cb[jd];
#pragma unroll
        for (int k = 0; k < KC; k++) {
#pragma unroll
            for (int jd = 0; jd < 8; jd++)
                acc[jd] += b2f((u16)xv[j + k][jd]) * w[jd][k];
        }
        short8 o;
#pragma unroll
        for (int jd = 0; jd < 8; jd++) {
            float s = acc[jd] / (1.f + __expf(-acc[jd]));
            o[jd] = (short)f2b(s);
        }
        *(short8*)(xs + (size_t)(m0 + j) * DI + d0) = o;
    }
}

// =====================================================================
// Chunked selective scan, NCHUNK=32 (1024 blocks).  Inter-chunk state
// compressed via P_s = exp(a_s * sum(dt)); p1 stores h_end + sdt; p2
// reconstructs P and runs in-place.
// =====================================================================
__global__ __launch_bounds__(256) void scan_p1(
    const u16* __restrict__ xzdt, const u16* __restrict__ xs,
    const float* __restrict__ bcf, const float* __restrict__ A_log,
    float* __restrict__ scr_h, float* __restrict__ sdt_g)
{
    __shared__ alignas(16) float bcs[LC * 32];   // 8 KB

    const int d = blockIdx.x * 256 + threadIdx.x;
    const int b = blockIdx.y;
    const int c = blockIdx.z;
    const int m0 = b * Ll + c * LC;

    {
        const float* bc_g = bcf + (size_t)m0 * 32;
#pragma unroll
        for (int j = 0; j < 2; j++) {
            int idx = j * 1024 + threadIdx.x * 4;
            *(floatx4*)(bcs + idx) = *(const floatx4*)(bc_g + idx);
        }
    }

    const float ad0 = -__expf(A_log[0]);
    float adl[DS];
    bool fast = true;
#pragma unroll
    for (int s = 0; s < DS; s++) {
        float av = -__expf(A_log[s]);
        adl[s] = av;
        float kr = (float)(s + 1);
        if (fabsf(av / ad0 - kr) > 1e-4f * kr) fast = false;
    }

    const u16* dt_p = xzdt + (size_t)m0 * LDXZ + d;
    const u16* xs_p = xs + (size_t)m0 * DI + d;

    float h[DS] = {};
    float sdt = 0.f;

    __syncthreads();

    u16 dt_c = dt_p[0],     xs_c = xs_p[0];
    u16 dt_1 = dt_p[LDXZ],  xs_1 = xs_p[DI];

    if (fast) {
        for (int l = 0; l < LC; l++) {
            u16 dt_2 = dt_p[2 * LDXZ];
            u16 xs_2 = xs_p[2 * DI];
            const float* bl = bcs + l * 32;
            floatx4 B0 = *(const floatx4*)(bl);
            floatx4 B1 = *(const floatx4*)(bl + 4);
            floatx4 B2 = *(const floatx4*)(bl + 8);
            floatx4 B3 = *(const floatx4*)(bl + 12);

            float dtv = b2f(dt_c);
            float xv  = b2f(xs_c);
            float bx = dtv * xv;
            sdt += dtv;
            float aa[DS];
            pow_tree(__expf(dtv * ad0), aa);
#pragma unroll
            for (int s = 0; s < DS; s++) {
                float Bv = (s < 4) ? B0[s] : (s < 8) ? B1[s - 4]
                         : (s < 12) ? B2[s - 8] : B3[s - 12];
                h[s] = aa[s] * h[s] + bx * Bv;
            }
            dt_c = dt_1; dt_1 = dt_2; xs_c = xs_1; xs_1 = xs_2;
            dt_p += LDXZ; xs_p += DI;
        }
    } else {
        for (int l = 0; l < LC; l++) {
            u16 dt_2 = dt_p[2 * LDXZ];
            u16 xs_2 = xs_p[2 * DI];
            const float* bl = bcs + l * 32;
            floatx4 B0 = *(const floatx4*)(bl);
            floatx4 B1 = *(const floatx4*)(bl + 4);
            floatx4 B2 = *(const floatx4*)(bl + 8);
            floatx4 B3 = *(const floatx4*)(bl + 12);

            float dtv = b2f(dt_c);
            float xv  = b2f(xs_c);
            float bx = dtv * xv;
            sdt += dtv;
#pragma unroll
            for (int s = 0; s < DS; s++) {
                float Bv = (s < 4) ? B0[s] : (s < 8) ? B1[s - 4]
                         : (s < 12) ? B2[s - 8] : B3[s - 12];
                float a = __expf(dtv * adl[s]);
                h[s] = a * h[s] + bx * Bv;
            }
            dt_c = dt_1; dt_1 = dt_2; xs_c = xs_1; xs_1 = xs_2;
            dt_p += LDXZ; xs_p += DI;
        }
    }

    const size_t base = ((size_t)(b * NCHUNK + c) * DI + d) * DS;
#pragma unroll
    for (int s = 0; s < DS; s += 4) {
        floatx4 hv = {h[s], h[s+1], h[s+2], h[s+3]};
        *(floatx4*)(scr_h + base + s) = hv;
    }
    sdt_g[(size_t)(b * NCHUNK + c) * DI + d] = sdt;
}

// in-place chunk-prefix: scr_h holds h_end on entry, h_in on exit
__global__ __launch_bounds__(256) void scan_p2(
    float* __restrict__ scr_h, const float* __restrict__ sdt_g,
    const float* __restrict__ A_log)
{
    const int t = blockIdx.x * 256 + threadIdx.x;   // (b, d, s)
    const int s = t & 15;
    const int d = (t >> 4) & (DI - 1);
    const int b = t >> 15;
    const float adl = -__expf(A_log[s]);

    float hin = 0.f;
    for (int c0 = 0; c0 < NCHUNK; c0 += 8) {
        float he[8], P[8];
#pragma unroll
        for (int j = 0; j < 8; j++) {
            const size_t base = ((size_t)(b * NCHUNK + c0 + j) * DI + d) * DS + s;
            he[j] = scr_h[base];
            P[j] = adl * sdt_g[(size_t)(b * NCHUNK + c0 + j) * DI + d];
        }
#pragma unroll
        for (int j = 0; j < 8; j++) P[j] = __expf(P[j]);
#pragma unroll
        for (int j = 0; j < 8; j++) {
            const size_t base = ((size_t)(b * NCHUNK + c0 + j) * DI + d) * DS + s;
            scr_h[base] = hin;
            hin = P[j] * hin + he[j];
        }
    }
}

__global__ __launch_bounds__(256) void scan_p3(
    const u16* __restrict__ xz, const u16* xs, const float* __restrict__ bcf,
    const float* __restrict__ scr_hin, const float* __restrict__ A_log,
    const float* __restrict__ Dvec, u16* yg)
{
    __shared__ alignas(16) float bcs[LC * 32];   // 8 KB

    const int d = blockIdx.x * 256 + threadIdx.x;
    const int b = blockIdx.y;
    const int c = blockIdx.z;
    const int m0 = b * Ll + c * LC;

    {
        const float* bc_g = bcf + (size_t)m0 * 32;
#pragma unroll
        for (int j = 0; j < 2; j++) {
            int idx = j * 1024 + threadIdx.x * 4;
            *(floatx4*)(bcs + idx) = *(const floatx4*)(bc_g + idx);
        }
    }

    const float ad0 = -__expf(A_log[0]);
    float adl[DS];
    bool fast = true;
#pragma unroll
    for (int s = 0; s < DS; s++) {
        float av = -__expf(A_log[s]);
        adl[s] = av;
        float kr = (float)(s + 1);
        if (fabsf(av / ad0 - kr) > 1e-4f * kr) fast = false;
    }
    const float Dd = Dvec[d];

    const u16* dt_p = xz + (size_t)m0 * LDXZ + d;
    const u16* z_p  = xz + (size_t)m0 * LDXZ + 2048 + d;
    const u16* xs_p = xs + (size_t)m0 * DI + d;
    u16* yg_p = yg + (size_t)m0 * DI + d;

    float h[DS];
    const size_t base = ((size_t)(b * NCHUNK + c) * DI + d) * DS;
#pragma unroll
    for (int s = 0; s < DS; s += 4) {
        floatx4 hv = *(const floatx4*)(scr_hin + base + s);
        h[s] = hv[0]; h[s+1] = hv[1]; h[s+2] = hv[2]; h[s+3] = hv[3];
    }

    __syncthreads();

    u16 dt_c = dt_p[0],    dt_1 = dt_p[LDXZ];
    u16 xs_c = xs_p[0],    xs_1 = xs_p[DI];
    u16 z_c  = z_p[0],     z_1  = z_p[LDXZ];

    for (int l = 0; l < LC; l++) {
        u16 dt_2 = dt_p[2 * LDXZ];
        u16 xs_2 = xs_p[2 * DI];
        u16 z_2  = z_p[2 * LDXZ];
        const float* bl = bcs + l * 32;
        floatx4 Bq[4], Cq[4];
#pragma unroll
        for (int q = 0; q < 4; q++) {
            Bq[q] = *(const floatx4*)(bl + q * 4);
            Cq[q] = *(const floatx4*)(bl + 16 + q * 4);
        }

        float dtv = b2f(dt_c);
        float xv  = b2f(xs_c);
        float bx = dtv * xv;
        float aa[DS];
        if (fast) {
            pow_tree(__expf(dtv * ad0), aa);
        } else {
#pragma unroll
            for (int s = 0; s < DS; s++) aa[s] = __expf(dtv * adl[s]);
        }
        float y0 = 0.f, y1 = 0.f, y2 = 0.f, y3 = 0.f;
#pragma unroll
        for (int q = 0; q < 4; q++) {
#pragma unroll
            for (int j = 0; j < 4; j++) {
                int s = q * 4 + j;
                h[s] = aa[s] * h[s] + bx * Bq[q][j];
            }
        }
#pragma unroll
        for (int j = 0; j < 4; j++) {
            y0 += h[j] * Cq[0][j];
            y1 += h[4 + j] * Cq[1][j];
            y2 += h[8 + j] * Cq[2][j];
            y3 += h[12 + j] * Cq[3][j];
        }
        float yt = ((y0 + y1) + (y2 + y3)) + Dd * xv;
        float zv = b2f(z_c);
        float g = zv / (1.f + __expf(-zv));
        yg_p[0] = f2b(yt * g);

        dt_c = dt_1; dt_1 = dt_2;
        xs_c = xs_1; xs_1 = xs_2;
        z_c  = z_1;  z_1  = z_2;
        dt_p += LDXZ; xs_p += DI; z_p += LDXZ; yg_p += DI;
    }
}

// =====================================================================
extern "C" void kernel_launch(void* const* d_in, const int* in_sizes, int n_in,
                              void* d_out, int out_size, void* d_ws, size_t ws_size,
                              hipStream_t stream)
{
    const float* x      = (const float*)d_in[0];
    const float* W_in   = (const float*)d_in[1];
    const float* conv_w = (const float*)d_in[2];
    const float* conv_b = (const float*)d_in[3];
    const float* A_log  = (const float*)d_in[4];
    const float* Dvec   = (const float*)d_in[5];
    const float* W_x    = (const float*)d_in[6];
    const float* W_dt   = (const float*)d_in[7];
    const float* b_dt   = (const float*)d_in[8];
    const float* W_out  = (const float*)d_in[9];

    // ---- workspace arena (bf16 u16 elements), ~133 MB total ----
    u16* ws = (u16*)d_ws;
    u16* xz    = ws;                 ws += (size_t)M * LDXZ;     // 67.1 MB
    u16* xs    = ws;                 ws += (size_t)M * DI;       // 33.55 MB (yg in-place)
    u16* xbf   = ws;                 ws += (size_t)M * DM;       // 16.78 MB
    u16* wibf  = ws;                 ws += (size_t)2 * DI * DM;  // 8.39 MB (reused as bcf+sdt)
    u16* wxp   = ws;                 ws += (size_t)NPAD * DI;    // 0.52 MB
    u16* wdtb  = ws;                 ws += (size_t)DI * DTR;     // 0.26 MB
    u16* woutb = ws;                 ws += (size_t)DM * DI;      // 4.19 MB
    u16* xdbl  = ws;                 ws += (size_t)M * NPAD;     // 2.10 MB (M*64 used)
    float* part  = (float*)xbf;      // split-K partials (xbf dead after GEMM1)
    float* scr_h = (float*)xbf;      // scan h scratch (part dead after redk)
    float* bcf   = (float*)wibf;     // 1.05 MB (wibf dead after GEMM1)
    float* sdt_g = bcf + (size_t)M * 32;   // 1.05 MB, inside wibf region

    // 0) merged operand prep
    {
        constexpr int NTOT = M * DM + 2 * DI * DM + NPAD * DI + DI * DTR + DM * DI;
        prep_all<<<NTOT / 256, 256, 0, stream>>>(
            x, W_in, W_x, W_dt, W_out, xbf, wibf, wxp, wdtb, woutb);
    }

    // 1) xz = x @ W_in^T   (8192 x 4096, K=1024)
    gemm256<0><<<dim3(LDXZ / 256, M / 256), 512, 0, stream>>>(
        xbf, wibf, xz, DM, DM, DM, LDXZ);

    // 2) conv + silu -> xs  (8 rows/block, 11-row register window)
    conv_silu8<<<M / 8, 256, 0, stream>>>(xz, conv_w, conv_b, xs);

    // 3) x_dbl partials = xs @ wxp^T, split-K x4 (cols 0..95), then reduce once
    gemm_bt<4><<<dim3(1, M / 128, 4), 256, 0, stream>>>(
        xs, wxp, part, nullptr, DI / 4, DI, DI, NPAD);
    redk_gemm3<<<(M * 24) / 256, 256, 0, stream>>>(part, xdbl, bcf);

    // 4) dt = fast-softplus(xdbl @ W_dt^T + b_dt) -> xr half of xz
    gemm_bt<2><<<dim3(DI / 128, M / 128), 256, 0, stream>>>(
        xdbl, wdtb, xz, b_dt, DTR, 64, DTR, LDXZ);

    // 5) chunked scan
    scan_p1<<<dim3(DI / 256, Bb, NCHUNK), 256, 0, stream>>>(
        xz, xs, bcf, A_log, scr_h, sdt_g);
    scan_p2<<<(Bb * DI * DS) / 256, 256, 0, stream>>>(scr_h, sdt_g, A_log);
    scan_p3<<<dim3(DI / 256, Bb, NCHUNK), 256, 0, stream>>>(
        xz, xs, bcf, scr_h, A_log, Dvec, xs);

    // 6) out = yg @ W_out^T   (8192 x 1024, K=2048), 2-tile phases
    gemm256n128<1><<<dim3(DM / 128, M / 256), 512, 0, stream>>>(
        xs, woutb, d_out, DI, DI, DI, DM);
}